// Round 5
// baseline (8849.886 us; speedup 1.0000x reference)
//
#include <hip/hip_runtime.h>
#include <cstdint>
#include <cstddef>

#define NN    20000
#define EM    100000
#define EBN   20000
#define WID   32
#define KW    64
#define KIN   6
#define NDEPTH 4
#define GC    2080   // 64*32 kernel cols + 32 bias cols
#define NB    8      // nodes per fuse-block
#define GROW  2084   // padded LDS row (2084 % 32 == 4 -> rows hit distinct bank quartets)

// ---------------- small setup kernels ----------------

__global__ void k_prep(const float* __restrict__ r1, const float* __restrict__ b1,
                       const float* __restrict__ r2, const float* __restrict__ b2,
                       float* __restrict__ rs, float* __restrict__ bs) {
    int i = threadIdx.x;
    if (i < 1024) rs[i] = r1[i] + r2[i];
    if (i < 32)   bs[i] = b1[i] + b2[i];
}

__global__ void k_h0(const float* __restrict__ x, const float* __restrict__ fc1w,
                     const float* __restrict__ fc1b, float* __restrict__ h0,
                     float* __restrict__ h) {
    int t = blockIdx.x * blockDim.x + threadIdx.x;
    if (t >= NN * WID) return;
    int node = t >> 5, j = t & 31;
    float v = x[node] * fc1w[j] + fc1b[j];
    h0[t] = v; h[t] = v;
}

__global__ void k_count(const int* __restrict__ idx, int E, int* __restrict__ cnt) {
    int e = blockIdx.x * blockDim.x + threadIdx.x;
    if (e < E) atomicAdd(&cnt[idx[e]], 1);
}

__global__ void k_inv(const int* __restrict__ cnt, float* __restrict__ inv, int n) {
    int i = blockIdx.x * blockDim.x + threadIdx.x;
    if (i < n) {
        int c = cnt[i]; if (c < 1) c = 1;
        inv[i] = 1.0f / (float)c;
    }
}

// combined scan over src-counts: edge-offset cursor (cur), active-node rank
// (arank), compacted active list (anodes), active CSR (aoff, aoff[na]=E), na.
__global__ __launch_bounds__(1024) void k_scan2(const int* __restrict__ cnt,
        int* __restrict__ cur, int* __restrict__ arank, int* __restrict__ anodes,
        int* __restrict__ aoff, int* __restrict__ dna, int n, int E) {
    __shared__ int part[1024];
    __shared__ int partf[1024];
    int t = threadIdx.x;
    int per = (n + 1023) / 1024;
    int base = t * per;
    int s = 0, f = 0;
    for (int i = 0; i < per; i++) {
        int idx = base + i;
        if (idx < n) { int c = cnt[idx]; s += c; f += (c > 0) ? 1 : 0; }
    }
    part[t] = s; partf[t] = f;
    __syncthreads();
    for (int od = 1; od < 1024; od <<= 1) {
        int v  = (t >= od) ? part[t - od] : 0;
        int vf = (t >= od) ? partf[t - od] : 0;
        __syncthreads();
        part[t] += v; partf[t] += vf;
        __syncthreads();
    }
    int run  = (t > 0) ? part[t - 1] : 0;
    int runf = (t > 0) ? partf[t - 1] : 0;
    for (int i = 0; i < per; i++) {
        int idx = base + i;
        if (idx < n) {
            int c = cnt[idx];
            cur[idx] = run;
            arank[idx] = runf;
            if (c > 0) { anodes[runf] = idx; aoff[runf] = run; runf++; }
            run += c;
        }
    }
    if (t == 1023) { dna[0] = partf[1023]; aoff[partf[1023]] = E; }
}

__global__ void k_scatter(const int* __restrict__ src, int E,
                          int* __restrict__ cur, int* __restrict__ perm) {
    int e = blockIdx.x * blockDim.x + threadIdx.x;
    if (e < E) { int p = atomicAdd(&cur[src[e]], 1); perm[p] = e; }
}

__global__ void k_permidx(const int* __restrict__ ei, int E,
                          const int* __restrict__ perm,
                          int* __restrict__ src_s, int* __restrict__ dst_s) {
    int i = blockIdx.x * blockDim.x + threadIdx.x;
    if (i >= E) return;
    int e = perm[i];
    src_s[i] = ei[e];
    dst_s[i] = ei[E + e];
}

// M[i][c*32+o] = w3[c][i*32+o] (c<64); M[i][2048+o] = b3[i*32+o]
__global__ void k_permM(const float* __restrict__ w3, const float* __restrict__ b3,
                        float* __restrict__ M) {
    int t = blockIdx.x * blockDim.x + threadIdx.x;
    if (t >= 32 * GC) return;
    int i = t / GC, c = t % GC;
    if (c < 2048) {
        int cc = c >> 5, o = c & 31;
        M[t] = w3[cc * 1024 + i * 32 + o];
    } else {
        M[t] = b3[i * 32 + (c - 2048)];
    }
}

// ---------------- edge MLP: ea(E x 6) -> K(E x 64), permuted order ----------------

__global__ __launch_bounds__(256) void k_mlp(const float* __restrict__ ea, int E,
        const float* __restrict__ w1, const float* __restrict__ b1,
        const float* __restrict__ w2, const float* __restrict__ b2,
        const int* __restrict__ perm, float* __restrict__ K) {
    __shared__ float sw1[KIN * KW];
    __shared__ float sw2[KW * KW];
    __shared__ float sb1[KW];
    __shared__ float sb2[KW];
    for (int i = threadIdx.x; i < KIN * KW; i += 256) sw1[i] = w1[i];
    for (int i = threadIdx.x; i < KW * KW; i += 256)  sw2[i] = w2[i];
    if (threadIdx.x < KW) { sb1[threadIdx.x] = b1[threadIdx.x]; sb2[threadIdx.x] = b2[threadIdx.x]; }
    __syncthreads();
    int e = blockIdx.x * 256 + threadIdx.x;
    if (e >= E) return;
    int eo = perm ? perm[e] : e;
    float a0 = ea[(size_t)eo * KIN + 0];
    float a1 = ea[(size_t)eo * KIN + 1];
    float a2 = ea[(size_t)eo * KIN + 2];
    float a3 = ea[(size_t)eo * KIN + 3];
    float a4 = ea[(size_t)eo * KIN + 4];
    float a5 = ea[(size_t)eo * KIN + 5];
    float t[KW];
#pragma unroll
    for (int j = 0; j < KW; j++) {
        float s = sb1[j];
        s += a0 * sw1[0 * KW + j];
        s += a1 * sw1[1 * KW + j];
        s += a2 * sw1[2 * KW + j];
        s += a3 * sw1[3 * KW + j];
        s += a4 * sw1[4 * KW + j];
        s += a5 * sw1[5 * KW + j];
        t[j] = fmaxf(s, 0.0f);
    }
#pragma unroll
    for (int h = 0; h < 2; h++) {
        int j0 = h * 32;
        float4 acc[8];
#pragma unroll
        for (int jj = 0; jj < 8; jj++)
            acc[jj] = *(const float4*)&sb2[j0 + jj * 4];
#pragma unroll
        for (int c = 0; c < KW; c++) {
            float tc = t[c];
#pragma unroll
            for (int jj = 0; jj < 8; jj++) {
                float4 w = *(const float4*)&sw2[c * KW + j0 + jj * 4];
                acc[jj].x += tc * w.x; acc[jj].y += tc * w.y;
                acc[jj].z += tc * w.z; acc[jj].w += tc * w.w;
            }
        }
#pragma unroll
        for (int jj = 0; jj < 8; jj++) {
            float4 r = acc[jj];
            r.x = fmaxf(r.x, 0.f); r.y = fmaxf(r.y, 0.f);
            r.z = fmaxf(r.z, 0.f); r.w = fmaxf(r.w, 0.f);
            *(float4*)&K[(size_t)e * KW + j0 + jj * 4] = r;
        }
    }
}

// ---------------- fused per-depth sweep (active-node compacted) ----------------
// Block owns NB=8 ACTIVE nodes. Phase A: G rows (8 x 2080) in LDS.
// Phase B: walk the block's contiguous src-sorted edge range,
// msg = sum_c K[e][c]*G[row][c*32+o] (+bias col), atomic mean-aggregate.

__global__ __launch_bounds__(512, 4) void k_fuse(const int* __restrict__ src_s,
        const int* __restrict__ dst_s, const int* __restrict__ aoff,
        const int* __restrict__ anodes, const int* __restrict__ arank,
        const int* __restrict__ dna, const float* __restrict__ Ks,
        const float* __restrict__ M, const float* __restrict__ h,
        float* __restrict__ agg) {
    __shared__ float sG[NB * GROW];   // 66.7 KB
    __shared__ float sHt[32 * NB];    // [k][r]
    int na = dna[0];
    int a0 = blockIdx.x * NB;
    if (a0 >= na) return;
    int t = threadIdx.x;
    {
        int r = t >> 5, k = t & 31;
        if (r < NB) {
            float v = 0.0f;
            if (a0 + r < na) v = h[(size_t)anodes[a0 + r] * WID + k];
            sHt[k * NB + r] = v;
        }
    }
    __syncthreads();
    // phase A: each thread one float4-column for all 8 rows; 520 cols / 512 thr
    for (int c4 = t; c4 < GC / 4; c4 += 512) {
        int col = c4 * 4;
        float4 acc[NB];
#pragma unroll
        for (int r = 0; r < NB; r++) acc[r] = make_float4(0.f, 0.f, 0.f, 0.f);
#pragma unroll
        for (int k = 0; k < 32; k++) {
            float4 mv = *(const float4*)&M[(size_t)k * GC + col];
            float4 h03 = *(const float4*)&sHt[k * NB + 0];
            float4 h47 = *(const float4*)&sHt[k * NB + 4];
            float hr[NB] = {h03.x, h03.y, h03.z, h03.w, h47.x, h47.y, h47.z, h47.w};
#pragma unroll
            for (int r = 0; r < NB; r++) {
                acc[r].x += hr[r] * mv.x; acc[r].y += hr[r] * mv.y;
                acc[r].z += hr[r] * mv.z; acc[r].w += hr[r] * mv.w;
            }
        }
#pragma unroll
        for (int r = 0; r < NB; r++)
            *(float4*)&sG[r * GROW + col] = acc[r];
    }
    __syncthreads();
    // phase B: 64 groups of 8 lanes, 1 edge per group per pass
    int e_lo = aoff[a0];
    int a1 = a0 + NB; if (a1 > na) a1 = na;
    int e_hi = aoff[a1];
    int g = t >> 3;
    int q4 = (t & 7) * 4;
    for (int e = e_lo + g; e < e_hi; e += 64) {
        int row = arank[src_s[e]] - a0;
        int dst = dst_s[e];
        const float* Kr = Ks + (size_t)e * KW;
        int gb = row * GROW;
        float4 v0 = *(const float4*)&sG[gb + 2048 + q4];   // bias-fold column
        float4 v1 = make_float4(0.f, 0.f, 0.f, 0.f);
        float4 v2 = v1, v3 = v1;
#pragma unroll
        for (int c4 = 0; c4 < 16; c4++) {
            float4 kv = *(const float4*)&Kr[c4 * 4];
            float4 g0 = *(const float4*)&sG[gb + (c4 * 4 + 0) * 32 + q4];
            float4 g1 = *(const float4*)&sG[gb + (c4 * 4 + 1) * 32 + q4];
            float4 g2 = *(const float4*)&sG[gb + (c4 * 4 + 2) * 32 + q4];
            float4 g3 = *(const float4*)&sG[gb + (c4 * 4 + 3) * 32 + q4];
            v0.x += kv.x * g0.x; v0.y += kv.x * g0.y; v0.z += kv.x * g0.z; v0.w += kv.x * g0.w;
            v1.x += kv.y * g1.x; v1.y += kv.y * g1.y; v1.z += kv.y * g1.z; v1.w += kv.y * g1.w;
            v2.x += kv.z * g2.x; v2.y += kv.z * g2.y; v2.z += kv.z * g2.z; v2.w += kv.z * g2.w;
            v3.x += kv.w * g3.x; v3.y += kv.w * g3.y; v3.z += kv.w * g3.z; v3.w += kv.w * g3.w;
        }
        float4 m;
        m.x = v0.x + v1.x + v2.x + v3.x;
        m.y = v0.y + v1.y + v2.y + v3.y;
        m.z = v0.z + v1.z + v2.z + v3.z;
        m.w = v0.w + v1.w + v2.w + v3.w;
        float* ap = agg + (size_t)dst * WID + q4;
        unsafeAtomicAdd(ap + 0, m.x);
        unsafeAtomicAdd(ap + 1, m.y);
        unsafeAtomicAdd(ap + 2, m.z);
        unsafeAtomicAdd(ap + 3, m.w);
    }
}

// ---------------- node update + output ----------------

__global__ __launch_bounds__(256) void k_node(const float* __restrict__ hin,
        float* __restrict__ hout,
        const float* __restrict__ agg1, const float* __restrict__ aggb,
        const float* __restrict__ inv1, const float* __restrict__ invb,
        const float* __restrict__ h0, const float* __restrict__ rs,
        const float* __restrict__ bs) {
    __shared__ float sR[1024];
    __shared__ float sB[32];
    for (int i = threadIdx.x; i < 1024; i += 256) sR[i] = rs[i];
    if (threadIdx.x < 32) sB[threadIdx.x] = bs[threadIdx.x];
    __syncthreads();
    int t = blockIdx.x * 256 + threadIdx.x;
    if (t >= NN * WID) return;
    int n = t >> 5, j = t & 31;
    float s = agg1[t] * inv1[n] + aggb[t] * invb[n] + sB[j];
    const float* hr = hin + (size_t)n * WID;
#pragma unroll
    for (int i = 0; i < 32; i++) s += hr[i] * sR[i * 32 + j];
    hout[t] = fmaxf(s, 0.0f) + h0[t];
}

__global__ void k_fc2(const float* __restrict__ h, const float* __restrict__ w,
                      const float* __restrict__ b, float* __restrict__ out) {
    int n = blockIdx.x * blockDim.x + threadIdx.x;
    if (n >= NN) return;
    const float4* hv = (const float4*)(h + (size_t)n * WID);
    const float4* wv = (const float4*)w;
    float s = b[0];
#pragma unroll
    for (int q = 0; q < 8; q++) {
        float4 a = hv[q], c = wv[q];
        s += a.x * c.x + a.y * c.y + a.z * c.z + a.w * c.w;
    }
    out[n] = s;
}

// ---------------- launch ----------------

extern "C" void kernel_launch(void* const* d_in, const int* in_sizes, int n_in,
                              void* d_out, int out_size, void* d_ws, size_t ws_size,
                              hipStream_t stream) {
    const float* x    = (const float*)d_in[0];
    const int*   ei   = (const int*)d_in[1];
    const float* ea   = (const float*)d_in[2];
    const int*   eib  = (const int*)d_in[3];
    const float* eab  = (const float*)d_in[4];
    const float* fc1w = (const float*)d_in[5];
    const float* fc1b = (const float*)d_in[6];
    const float* fc2w = (const float*)d_in[7];
    const float* fc2b = (const float*)d_in[8];
    const float* k1w1 = (const float*)d_in[9];
    const float* k1b1 = (const float*)d_in[10];
    const float* k1w2 = (const float*)d_in[11];
    const float* k1b2 = (const float*)d_in[12];
    const float* k1w3 = (const float*)d_in[13];
    const float* k1b3 = (const float*)d_in[14];
    const float* root1= (const float*)d_in[15];
    const float* bias1= (const float*)d_in[16];
    const float* k2w1 = (const float*)d_in[17];
    const float* k2b1 = (const float*)d_in[18];
    const float* k2w2 = (const float*)d_in[19];
    const float* k2b2 = (const float*)d_in[20];
    const float* k2w3 = (const float*)d_in[21];
    const float* k2b3 = (const float*)d_in[22];
    const float* root2= (const float*)d_in[23];
    const float* bias2= (const float*)d_in[24];

    float* p = (float*)d_ws;
    auto alloc = [&](size_t nflt) { float* r = p; p += nflt; return r; };
    float* K1   = alloc((size_t)EM * KW);     // sorted (by src) order
    float* Kb   = alloc((size_t)EBN * KW);
    float* h0   = alloc((size_t)NN * WID);
    float* hA   = alloc((size_t)NN * WID);
    float* hB   = alloc((size_t)NN * WID);
    float* agg1 = alloc((size_t)NN * WID);    // agg1+aggb contiguous: single memset
    float* aggb = alloc((size_t)NN * WID);
    float* inv1 = alloc(NN);
    float* invb = alloc(NN);
    float* rs   = alloc(1024);
    float* bs   = alloc(32);
    int*   cnt1 = (int*)alloc(NN);   // cnt1,cntb,cs1,csb contiguous: single memset
    int*   cntb = (int*)alloc(NN);
    int*   cs1  = (int*)alloc(NN);
    int*   csb  = (int*)alloc(NN);
    int*   cur1 = (int*)alloc(NN);
    int*   curb = (int*)alloc(NN);
    int*   arank1 = (int*)alloc(NN);
    int*   arankb = (int*)alloc(NN);
    int*   anodes1= (int*)alloc(NN);
    int*   anodesb= (int*)alloc(NN);
    int*   aoff1  = (int*)alloc(NN + 1);
    int*   aoffb  = (int*)alloc(NN + 1);
    int*   dna1   = (int*)alloc(1);
    int*   dnab   = (int*)alloc(1);
    int*   perm1= (int*)alloc(EM);
    int*   permb= (int*)alloc(EBN);
    int*   srcs1= (int*)alloc(EM);
    int*   dsts1= (int*)alloc(EM);
    int*   srcsb= (int*)alloc(EBN);
    int*   dstsb= (int*)alloc(EBN);
    float* M1   = alloc(32 * GC);
    float* M2   = alloc(32 * GC);

    hipMemsetAsync(cnt1, 0, 4 * NN * sizeof(int), stream);
    k_prep<<<1, 1024, 0, stream>>>(root1, bias1, root2, bias2, rs, bs);
    k_h0<<<(NN * WID + 255) / 256, 256, 0, stream>>>(x, fc1w, fc1b, h0, hA);
    k_count<<<(EM + 255) / 256, 256, 0, stream>>>(ei + EM, EM, cnt1);     // dst counts
    k_count<<<(EBN + 255) / 256, 256, 0, stream>>>(eib + EBN, EBN, cntb);
    k_inv<<<(NN + 255) / 256, 256, 0, stream>>>(cnt1, inv1, NN);
    k_inv<<<(NN + 255) / 256, 256, 0, stream>>>(cntb, invb, NN);
    k_count<<<(EM + 255) / 256, 256, 0, stream>>>(ei, EM, cs1);           // src counts
    k_count<<<(EBN + 255) / 256, 256, 0, stream>>>(eib, EBN, csb);
    k_scan2<<<1, 1024, 0, stream>>>(cs1, cur1, arank1, anodes1, aoff1, dna1, NN, EM);
    k_scan2<<<1, 1024, 0, stream>>>(csb, curb, arankb, anodesb, aoffb, dnab, NN, EBN);
    k_scatter<<<(EM + 255) / 256, 256, 0, stream>>>(ei, EM, cur1, perm1);
    k_scatter<<<(EBN + 255) / 256, 256, 0, stream>>>(eib, EBN, curb, permb);
    k_permidx<<<(EM + 255) / 256, 256, 0, stream>>>(ei, EM, perm1, srcs1, dsts1);
    k_permidx<<<(EBN + 255) / 256, 256, 0, stream>>>(eib, EBN, permb, srcsb, dstsb);
    k_mlp<<<(EM + 255) / 256, 256, 0, stream>>>(ea, EM, k1w1, k1b1, k1w2, k1b2, perm1, K1);
    k_mlp<<<(EBN + 255) / 256, 256, 0, stream>>>(eab, EBN, k2w1, k2b1, k2w2, k2b2, permb, Kb);
    k_permM<<<(32 * GC + 255) / 256, 256, 0, stream>>>(k1w3, k1b3, M1);
    k_permM<<<(32 * GC + 255) / 256, 256, 0, stream>>>(k2w3, k2b3, M2);

    const float* hin = hA;
    float* hout = hB;
    int fgrid = (NN + NB - 1) / NB;   // blocks past na early-exit
    for (int d = 0; d < NDEPTH; d++) {
        hipMemsetAsync(agg1, 0, (size_t)2 * NN * WID * sizeof(float), stream);
        k_fuse<<<fgrid, 512, 0, stream>>>(srcs1, dsts1, aoff1, anodes1, arank1,
                                          dna1, K1, M1, hin, agg1);
        k_fuse<<<fgrid, 512, 0, stream>>>(srcsb, dstsb, aoffb, anodesb, arankb,
                                          dnab, Kb, M2, hin, aggb);
        k_node<<<(NN * WID + 255) / 256, 256, 0, stream>>>(hin, hout, agg1, aggb,
                                                           inv1, invb, h0, rs, bs);
        float* tmp = (float*)hin; hin = hout; hout = tmp;
    }
    k_fc2<<<(NN + 255) / 256, 256, 0, stream>>>(hin, fc2w, fc2b, (float*)d_out);
}

// Round 6
// 980.854 us; speedup vs baseline: 9.0226x; 9.0226x over previous
//
#include <hip/hip_runtime.h>
#include <cstdint>
#include <cstddef>

#define NN    20000
#define EM    100000
#define EBN   20000
#define WID   32
#define KW    64
#define KIN   6
#define NDEPTH 4
#define GC    2080   // 64*32 kernel cols + 32 bias cols
#define NB    8      // nodes per fuse-block
#define GROW  2084   // padded LDS row

// ---------------- small setup kernels ----------------

__global__ void k_prep(const float* __restrict__ r1, const float* __restrict__ b1,
                       const float* __restrict__ r2, const float* __restrict__ b2,
                       float* __restrict__ rs, float* __restrict__ bs) {
    int i = threadIdx.x;
    if (i < 1024) rs[i] = r1[i] + r2[i];
    if (i < 32)   bs[i] = b1[i] + b2[i];
}

__global__ void k_h0(const float* __restrict__ x, const float* __restrict__ fc1w,
                     const float* __restrict__ fc1b, float* __restrict__ h0,
                     float* __restrict__ h) {
    int t = blockIdx.x * blockDim.x + threadIdx.x;
    if (t >= NN * WID) return;
    int node = t >> 5, j = t & 31;
    float v = x[node] * fc1w[j] + fc1b[j];
    h0[t] = v; h[t] = v;
}

__global__ void k_count(const int* __restrict__ idx, int E, int* __restrict__ cnt) {
    int e = blockIdx.x * blockDim.x + threadIdx.x;
    if (e < E) atomicAdd(&cnt[idx[e]], 1);
}

__global__ void k_inv(const int* __restrict__ cnt, float* __restrict__ inv, int n) {
    int i = blockIdx.x * blockDim.x + threadIdx.x;
    if (i < n) {
        int c = cnt[i]; if (c < 1) c = 1;
        inv[i] = 1.0f / (float)c;
    }
}

// combined scan over src-counts: edge-offset cursor (cur), active-node rank
// (arank), compacted active list (anodes), active CSR (aoff, aoff[na]=E), na.
__global__ __launch_bounds__(1024) void k_scan2(const int* __restrict__ cnt,
        int* __restrict__ cur, int* __restrict__ arank, int* __restrict__ anodes,
        int* __restrict__ aoff, int* __restrict__ dna, int n, int E) {
    __shared__ int part[1024];
    __shared__ int partf[1024];
    int t = threadIdx.x;
    int per = (n + 1023) / 1024;
    int base = t * per;
    int s = 0, f = 0;
    for (int i = 0; i < per; i++) {
        int idx = base + i;
        if (idx < n) { int c = cnt[idx]; s += c; f += (c > 0) ? 1 : 0; }
    }
    part[t] = s; partf[t] = f;
    __syncthreads();
    for (int od = 1; od < 1024; od <<= 1) {
        int v  = (t >= od) ? part[t - od] : 0;
        int vf = (t >= od) ? partf[t - od] : 0;
        __syncthreads();
        part[t] += v; partf[t] += vf;
        __syncthreads();
    }
    int run  = (t > 0) ? part[t - 1] : 0;
    int runf = (t > 0) ? partf[t - 1] : 0;
    for (int i = 0; i < per; i++) {
        int idx = base + i;
        if (idx < n) {
            int c = cnt[idx];
            cur[idx] = run;
            arank[idx] = runf;
            if (c > 0) { anodes[runf] = idx; aoff[runf] = run; runf++; }
            run += c;
        }
    }
    if (t == 1023) { dna[0] = partf[1023]; aoff[partf[1023]] = E; }
}

__global__ void k_scatter(const int* __restrict__ src, int E,
                          int* __restrict__ cur, int* __restrict__ perm) {
    int e = blockIdx.x * blockDim.x + threadIdx.x;
    if (e < E) { int p = atomicAdd(&cur[src[e]], 1); perm[p] = e; }
}

__global__ void k_permidx(const int* __restrict__ ei, int E,
                          const int* __restrict__ perm,
                          int* __restrict__ src_s, int* __restrict__ dst_s) {
    int i = blockIdx.x * blockDim.x + threadIdx.x;
    if (i >= E) return;
    int e = perm[i];
    src_s[i] = ei[e];
    dst_s[i] = ei[E + e];
}

// M[i][c*32+o] = w3[c][i*32+o] (c<64); M[i][2048+o] = b3[i*32+o]
__global__ void k_permM(const float* __restrict__ w3, const float* __restrict__ b3,
                        float* __restrict__ M) {
    int t = blockIdx.x * blockDim.x + threadIdx.x;
    if (t >= 32 * GC) return;
    int i = t / GC, c = t % GC;
    if (c < 2048) {
        int cc = c >> 5, o = c & 31;
        M[t] = w3[cc * 1024 + i * 32 + o];
    } else {
        M[t] = b3[i * 32 + (c - 2048)];
    }
}

// ---------------- edge MLP: ea(E x 6) -> K(E x 64), permuted order ----------------

__global__ __launch_bounds__(256) void k_mlp(const float* __restrict__ ea, int E,
        const float* __restrict__ w1, const float* __restrict__ b1,
        const float* __restrict__ w2, const float* __restrict__ b2,
        const int* __restrict__ perm, float* __restrict__ K) {
    __shared__ float sw1[KIN * KW];
    __shared__ float sw2[KW * KW];
    __shared__ float sb1[KW];
    __shared__ float sb2[KW];
    for (int i = threadIdx.x; i < KIN * KW; i += 256) sw1[i] = w1[i];
    for (int i = threadIdx.x; i < KW * KW; i += 256)  sw2[i] = w2[i];
    if (threadIdx.x < KW) { sb1[threadIdx.x] = b1[threadIdx.x]; sb2[threadIdx.x] = b2[threadIdx.x]; }
    __syncthreads();
    int e = blockIdx.x * 256 + threadIdx.x;
    if (e >= E) return;
    int eo = perm ? perm[e] : e;
    float a0 = ea[(size_t)eo * KIN + 0];
    float a1 = ea[(size_t)eo * KIN + 1];
    float a2 = ea[(size_t)eo * KIN + 2];
    float a3 = ea[(size_t)eo * KIN + 3];
    float a4 = ea[(size_t)eo * KIN + 4];
    float a5 = ea[(size_t)eo * KIN + 5];
    float t[KW];
#pragma unroll
    for (int j = 0; j < KW; j++) {
        float s = sb1[j];
        s += a0 * sw1[0 * KW + j];
        s += a1 * sw1[1 * KW + j];
        s += a2 * sw1[2 * KW + j];
        s += a3 * sw1[3 * KW + j];
        s += a4 * sw1[4 * KW + j];
        s += a5 * sw1[5 * KW + j];
        t[j] = fmaxf(s, 0.0f);
    }
#pragma unroll
    for (int h = 0; h < 2; h++) {
        int j0 = h * 32;
        float4 acc[8];
#pragma unroll
        for (int jj = 0; jj < 8; jj++)
            acc[jj] = *(const float4*)&sb2[j0 + jj * 4];
#pragma unroll
        for (int c = 0; c < KW; c++) {
            float tc = t[c];
#pragma unroll
            for (int jj = 0; jj < 8; jj++) {
                float4 w = *(const float4*)&sw2[c * KW + j0 + jj * 4];
                acc[jj].x += tc * w.x; acc[jj].y += tc * w.y;
                acc[jj].z += tc * w.z; acc[jj].w += tc * w.w;
            }
        }
#pragma unroll
        for (int jj = 0; jj < 8; jj++) {
            float4 r = acc[jj];
            r.x = fmaxf(r.x, 0.f); r.y = fmaxf(r.y, 0.f);
            r.z = fmaxf(r.z, 0.f); r.w = fmaxf(r.w, 0.f);
            *(float4*)&K[(size_t)e * KW + j0 + jj * 4] = r;
        }
    }
}

// ---------------- fused per-depth sweep (active-node compacted) ----------------
// 512 threads, 2 blocks/CU (LDS-capped) -> 16 waves/CU.
// Phase A: G rows (8 x 2080) in LDS; thread owns 4 rows x 4 cols (16 acc regs);
// thread halves t<256 / t>=256 cover rows 0-3 / 4-7 of the same column.
// Phase B: contiguous src-sorted edge range, 64 groups of 8 lanes.

__global__ __launch_bounds__(512, 2) void k_fuse(const int* __restrict__ src_s,
        const int* __restrict__ dst_s, const int* __restrict__ aoff,
        const int* __restrict__ anodes, const int* __restrict__ arank,
        const int* __restrict__ dna, const float* __restrict__ Ks,
        const float* __restrict__ M, const float* __restrict__ h,
        float* __restrict__ agg) {
    __shared__ float sG[NB * GROW];   // 66.7 KB
    __shared__ float sHt[32 * NB];    // [k][r]
    int na = dna[0];
    int a0 = blockIdx.x * NB;
    if (a0 >= na) return;
    int t = threadIdx.x;
    {
        int r = t >> 5, k = t & 31;
        if (r < NB) {
            float v = 0.0f;
            if (a0 + r < na) v = h[(size_t)anodes[a0 + r] * WID + k];
            sHt[k * NB + r] = v;
        }
    }
    __syncthreads();
    // phase A: 3 static passes; col = c0 + (t&255)*4; rows r0..r0+3
    {
        int half = t >> 8;        // 0 or 1
        int ct = t & 255;
        int r0 = half * 4;        // 0 or 4
#pragma unroll
        for (int c0 = 0; c0 < GC; c0 += 1024) {
            int col = c0 + ct * 4;
            if (col < GC) {
                float4 a0v = make_float4(0.f, 0.f, 0.f, 0.f);
                float4 a1v = a0v, a2v = a0v, a3v = a0v;
#pragma unroll
                for (int k = 0; k < 32; k++) {
                    float4 mv = *(const float4*)&M[(size_t)k * GC + col];
                    float4 hv = *(const float4*)&sHt[k * NB + r0];
                    a0v.x += hv.x * mv.x; a0v.y += hv.x * mv.y; a0v.z += hv.x * mv.z; a0v.w += hv.x * mv.w;
                    a1v.x += hv.y * mv.x; a1v.y += hv.y * mv.y; a1v.z += hv.y * mv.z; a1v.w += hv.y * mv.w;
                    a2v.x += hv.z * mv.x; a2v.y += hv.z * mv.y; a2v.z += hv.z * mv.z; a2v.w += hv.z * mv.w;
                    a3v.x += hv.w * mv.x; a3v.y += hv.w * mv.y; a3v.z += hv.w * mv.z; a3v.w += hv.w * mv.w;
                }
                *(float4*)&sG[(r0 + 0) * GROW + col] = a0v;
                *(float4*)&sG[(r0 + 1) * GROW + col] = a1v;
                *(float4*)&sG[(r0 + 2) * GROW + col] = a2v;
                *(float4*)&sG[(r0 + 3) * GROW + col] = a3v;
            }
        }
    }
    __syncthreads();
    // phase B: 64 groups of 8 lanes, 1 edge per group per pass
    int e_lo = aoff[a0];
    int a1 = a0 + NB; if (a1 > na) a1 = na;
    int e_hi = aoff[a1];
    int g = t >> 3;
    int q4 = (t & 7) * 4;
    for (int e = e_lo + g; e < e_hi; e += 64) {
        int row = arank[src_s[e]] - a0;
        int dst = dst_s[e];
        const float* Kr = Ks + (size_t)e * KW;
        int gb = row * GROW;
        float4 v0 = *(const float4*)&sG[gb + 2048 + q4];   // bias-fold column
        float4 v1 = make_float4(0.f, 0.f, 0.f, 0.f);
        float4 v2 = v1, v3 = v1;
#pragma unroll
        for (int c4 = 0; c4 < 16; c4++) {
            float4 kv = *(const float4*)&Kr[c4 * 4];
            float4 g0 = *(const float4*)&sG[gb + (c4 * 4 + 0) * 32 + q4];
            float4 g1 = *(const float4*)&sG[gb + (c4 * 4 + 1) * 32 + q4];
            float4 g2 = *(const float4*)&sG[gb + (c4 * 4 + 2) * 32 + q4];
            float4 g3 = *(const float4*)&sG[gb + (c4 * 4 + 3) * 32 + q4];
            v0.x += kv.x * g0.x; v0.y += kv.x * g0.y; v0.z += kv.x * g0.z; v0.w += kv.x * g0.w;
            v1.x += kv.y * g1.x; v1.y += kv.y * g1.y; v1.z += kv.y * g1.z; v1.w += kv.y * g1.w;
            v2.x += kv.z * g2.x; v2.y += kv.z * g2.y; v2.z += kv.z * g2.z; v2.w += kv.z * g2.w;
            v3.x += kv.w * g3.x; v3.y += kv.w * g3.y; v3.z += kv.w * g3.z; v3.w += kv.w * g3.w;
        }
        float4 m;
        m.x = v0.x + v1.x + v2.x + v3.x;
        m.y = v0.y + v1.y + v2.y + v3.y;
        m.z = v0.z + v1.z + v2.z + v3.z;
        m.w = v0.w + v1.w + v2.w + v3.w;
        float* ap = agg + (size_t)dst * WID + q4;
        unsafeAtomicAdd(ap + 0, m.x);
        unsafeAtomicAdd(ap + 1, m.y);
        unsafeAtomicAdd(ap + 2, m.z);
        unsafeAtomicAdd(ap + 3, m.w);
    }
}

// ---------------- node update + output ----------------

__global__ __launch_bounds__(256) void k_node(const float* __restrict__ hin,
        float* __restrict__ hout,
        const float* __restrict__ agg1, const float* __restrict__ aggb,
        const float* __restrict__ inv1, const float* __restrict__ invb,
        const float* __restrict__ h0, const float* __restrict__ rs,
        const float* __restrict__ bs) {
    __shared__ float sR[1024];
    __shared__ float sB[32];
    for (int i = threadIdx.x; i < 1024; i += 256) sR[i] = rs[i];
    if (threadIdx.x < 32) sB[threadIdx.x] = bs[threadIdx.x];
    __syncthreads();
    int t = blockIdx.x * 256 + threadIdx.x;
    if (t >= NN * WID) return;
    int n = t >> 5, j = t & 31;
    float s = agg1[t] * inv1[n] + aggb[t] * invb[n] + sB[j];
    const float* hr = hin + (size_t)n * WID;
#pragma unroll
    for (int i = 0; i < 32; i++) s += hr[i] * sR[i * 32 + j];
    hout[t] = fmaxf(s, 0.0f) + h0[t];
}

__global__ void k_fc2(const float* __restrict__ h, const float* __restrict__ w,
                      const float* __restrict__ b, float* __restrict__ out) {
    int n = blockIdx.x * blockDim.x + threadIdx.x;
    if (n >= NN) return;
    const float4* hv = (const float4*)(h + (size_t)n * WID);
    const float4* wv = (const float4*)w;
    float s = b[0];
#pragma unroll
    for (int q = 0; q < 8; q++) {
        float4 a = hv[q], c = wv[q];
        s += a.x * c.x + a.y * c.y + a.z * c.z + a.w * c.w;
    }
    out[n] = s;
}

// ---------------- launch ----------------

extern "C" void kernel_launch(void* const* d_in, const int* in_sizes, int n_in,
                              void* d_out, int out_size, void* d_ws, size_t ws_size,
                              hipStream_t stream) {
    const float* x    = (const float*)d_in[0];
    const int*   ei   = (const int*)d_in[1];
    const float* ea   = (const float*)d_in[2];
    const int*   eib  = (const int*)d_in[3];
    const float* eab  = (const float*)d_in[4];
    const float* fc1w = (const float*)d_in[5];
    const float* fc1b = (const float*)d_in[6];
    const float* fc2w = (const float*)d_in[7];
    const float* fc2b = (const float*)d_in[8];
    const float* k1w1 = (const float*)d_in[9];
    const float* k1b1 = (const float*)d_in[10];
    const float* k1w2 = (const float*)d_in[11];
    const float* k1b2 = (const float*)d_in[12];
    const float* k1w3 = (const float*)d_in[13];
    const float* k1b3 = (const float*)d_in[14];
    const float* root1= (const float*)d_in[15];
    const float* bias1= (const float*)d_in[16];
    const float* k2w1 = (const float*)d_in[17];
    const float* k2b1 = (const float*)d_in[18];
    const float* k2w2 = (const float*)d_in[19];
    const float* k2b2 = (const float*)d_in[20];
    const float* k2w3 = (const float*)d_in[21];
    const float* k2b3 = (const float*)d_in[22];
    const float* root2= (const float*)d_in[23];
    const float* bias2= (const float*)d_in[24];

    float* p = (float*)d_ws;
    auto alloc = [&](size_t nflt) { float* r = p; p += nflt; return r; };
    float* K1   = alloc((size_t)EM * KW);     // sorted (by src) order
    float* Kb   = alloc((size_t)EBN * KW);
    float* h0   = alloc((size_t)NN * WID);
    float* hA   = alloc((size_t)NN * WID);
    float* hB   = alloc((size_t)NN * WID);
    float* agg1 = alloc((size_t)NN * WID);    // agg1+aggb contiguous: single memset
    float* aggb = alloc((size_t)NN * WID);
    float* inv1 = alloc(NN);
    float* invb = alloc(NN);
    float* rs   = alloc(1024);
    float* bs   = alloc(32);
    int*   cnt1 = (int*)alloc(NN);   // cnt1,cntb,cs1,csb contiguous: single memset
    int*   cntb = (int*)alloc(NN);
    int*   cs1  = (int*)alloc(NN);
    int*   csb  = (int*)alloc(NN);
    int*   cur1 = (int*)alloc(NN);
    int*   curb = (int*)alloc(NN);
    int*   arank1 = (int*)alloc(NN);
    int*   arankb = (int*)alloc(NN);
    int*   anodes1= (int*)alloc(NN);
    int*   anodesb= (int*)alloc(NN);
    int*   aoff1  = (int*)alloc(NN + 1);
    int*   aoffb  = (int*)alloc(NN + 1);
    int*   dna1   = (int*)alloc(1);
    int*   dnab   = (int*)alloc(1);
    int*   perm1= (int*)alloc(EM);
    int*   permb= (int*)alloc(EBN);
    int*   srcs1= (int*)alloc(EM);
    int*   dsts1= (int*)alloc(EM);
    int*   srcsb= (int*)alloc(EBN);
    int*   dstsb= (int*)alloc(EBN);
    float* M1   = alloc(32 * GC);
    float* M2   = alloc(32 * GC);

    hipMemsetAsync(cnt1, 0, 4 * NN * sizeof(int), stream);
    k_prep<<<1, 1024, 0, stream>>>(root1, bias1, root2, bias2, rs, bs);
    k_h0<<<(NN * WID + 255) / 256, 256, 0, stream>>>(x, fc1w, fc1b, h0, hA);
    k_count<<<(EM + 255) / 256, 256, 0, stream>>>(ei + EM, EM, cnt1);     // dst counts
    k_count<<<(EBN + 255) / 256, 256, 0, stream>>>(eib + EBN, EBN, cntb);
    k_inv<<<(NN + 255) / 256, 256, 0, stream>>>(cnt1, inv1, NN);
    k_inv<<<(NN + 255) / 256, 256, 0, stream>>>(cntb, invb, NN);
    k_count<<<(EM + 255) / 256, 256, 0, stream>>>(ei, EM, cs1);           // src counts
    k_count<<<(EBN + 255) / 256, 256, 0, stream>>>(eib, EBN, csb);
    k_scan2<<<1, 1024, 0, stream>>>(cs1, cur1, arank1, anodes1, aoff1, dna1, NN, EM);
    k_scan2<<<1, 1024, 0, stream>>>(csb, curb, arankb, anodesb, aoffb, dnab, NN, EBN);
    k_scatter<<<(EM + 255) / 256, 256, 0, stream>>>(ei, EM, cur1, perm1);
    k_scatter<<<(EBN + 255) / 256, 256, 0, stream>>>(eib, EBN, curb, permb);
    k_permidx<<<(EM + 255) / 256, 256, 0, stream>>>(ei, EM, perm1, srcs1, dsts1);
    k_permidx<<<(EBN + 255) / 256, 256, 0, stream>>>(eib, EBN, permb, srcsb, dstsb);
    k_mlp<<<(EM + 255) / 256, 256, 0, stream>>>(ea, EM, k1w1, k1b1, k1w2, k1b2, perm1, K1);
    k_mlp<<<(EBN + 255) / 256, 256, 0, stream>>>(eab, EBN, k2w1, k2b1, k2w2, k2b2, permb, Kb);
    k_permM<<<(32 * GC + 255) / 256, 256, 0, stream>>>(k1w3, k1b3, M1);
    k_permM<<<(32 * GC + 255) / 256, 256, 0, stream>>>(k2w3, k2b3, M2);

    const float* hin = hA;
    float* hout = hB;
    int fgrid = (NN + NB - 1) / NB;   // blocks past na early-exit
    for (int d = 0; d < NDEPTH; d++) {
        hipMemsetAsync(agg1, 0, (size_t)2 * NN * WID * sizeof(float), stream);
        k_fuse<<<fgrid, 512, 0, stream>>>(srcs1, dsts1, aoff1, anodes1, arank1,
                                          dna1, K1, M1, hin, agg1);
        k_fuse<<<fgrid, 512, 0, stream>>>(srcsb, dstsb, aoffb, anodesb, arankb,
                                          dnab, Kb, M2, hin, aggb);
        k_node<<<(NN * WID + 255) / 256, 256, 0, stream>>>(hin, hout, agg1, aggb,
                                                           inv1, invb, h0, rs, bs);
        float* tmp = (float*)hin; hin = hout; hout = tmp;
    }
    k_fc2<<<(NN + 255) / 256, 256, 0, stream>>>(hin, fc2w, fc2b, (float*)d_out);
}

// Round 7
// 802.570 us; speedup vs baseline: 11.0269x; 1.2221x over previous
//
#include <hip/hip_runtime.h>
#include <cstdint>
#include <cstddef>

#define NN    20000
#define EM    100000
#define EBN   20000
#define WID   32
#define KW    64
#define KIN   6
#define NDEPTH 4
#define GC    2080   // 64*32 kernel cols + 32 bias cols
#define NB2   16     // nodes per fuse-block
#define GROW  2084   // padded LDS row

// ---------------- small setup kernels ----------------

__global__ void k_prep(const float* __restrict__ r1, const float* __restrict__ b1,
                       const float* __restrict__ r2, const float* __restrict__ b2,
                       float* __restrict__ rs, float* __restrict__ bs) {
    int i = threadIdx.x;
    if (i < 1024) rs[i] = r1[i] + r2[i];
    if (i < 32)   bs[i] = b1[i] + b2[i];
}

__global__ void k_h0(const float* __restrict__ x, const float* __restrict__ fc1w,
                     const float* __restrict__ fc1b, float* __restrict__ h0,
                     float* __restrict__ h) {
    int t = blockIdx.x * blockDim.x + threadIdx.x;
    if (t >= NN * WID) return;
    int node = t >> 5, j = t & 31;
    float v = x[node] * fc1w[j] + fc1b[j];
    h0[t] = v; h[t] = v;
}

__global__ void k_count(const int* __restrict__ idx, int E, int* __restrict__ cnt) {
    int e = blockIdx.x * blockDim.x + threadIdx.x;
    if (e < E) atomicAdd(&cnt[idx[e]], 1);
}

__global__ void k_inv(const int* __restrict__ cnt, float* __restrict__ inv, int n) {
    int i = blockIdx.x * blockDim.x + threadIdx.x;
    if (i < n) {
        int c = cnt[i]; if (c < 1) c = 1;
        inv[i] = 1.0f / (float)c;
    }
}

// combined scan over src-counts: edge-offset cursor (cur), active-node rank
// (arank), compacted active list (anodes), active CSR (aoff, aoff[na]=E), na.
__global__ __launch_bounds__(1024) void k_scan2(const int* __restrict__ cnt,
        int* __restrict__ cur, int* __restrict__ arank, int* __restrict__ anodes,
        int* __restrict__ aoff, int* __restrict__ dna, int n, int E) {
    __shared__ int part[1024];
    __shared__ int partf[1024];
    int t = threadIdx.x;
    int per = (n + 1023) / 1024;
    int base = t * per;
    int s = 0, f = 0;
    for (int i = 0; i < per; i++) {
        int idx = base + i;
        if (idx < n) { int c = cnt[idx]; s += c; f += (c > 0) ? 1 : 0; }
    }
    part[t] = s; partf[t] = f;
    __syncthreads();
    for (int od = 1; od < 1024; od <<= 1) {
        int v  = (t >= od) ? part[t - od] : 0;
        int vf = (t >= od) ? partf[t - od] : 0;
        __syncthreads();
        part[t] += v; partf[t] += vf;
        __syncthreads();
    }
    int run  = (t > 0) ? part[t - 1] : 0;
    int runf = (t > 0) ? partf[t - 1] : 0;
    for (int i = 0; i < per; i++) {
        int idx = base + i;
        if (idx < n) {
            int c = cnt[idx];
            cur[idx] = run;
            arank[idx] = runf;
            if (c > 0) { anodes[runf] = idx; aoff[runf] = run; runf++; }
            run += c;
        }
    }
    if (t == 1023) { dna[0] = partf[1023]; aoff[partf[1023]] = E; }
}

__global__ void k_scatter(const int* __restrict__ src, int E,
                          int* __restrict__ cur, int* __restrict__ perm) {
    int e = blockIdx.x * blockDim.x + threadIdx.x;
    if (e < E) { int p = atomicAdd(&cur[src[e]], 1); perm[p] = e; }
}

__global__ void k_permidx(const int* __restrict__ ei, int E,
                          const int* __restrict__ perm,
                          int* __restrict__ src_s, int* __restrict__ dst_s) {
    int i = blockIdx.x * blockDim.x + threadIdx.x;
    if (i >= E) return;
    int e = perm[i];
    src_s[i] = ei[e];
    dst_s[i] = ei[E + e];
}

// M[i][c*32+o] = w3[c][i*32+o] (c<64); M[i][2048+o] = b3[i*32+o]
__global__ void k_permM(const float* __restrict__ w3, const float* __restrict__ b3,
                        float* __restrict__ M) {
    int t = blockIdx.x * blockDim.x + threadIdx.x;
    if (t >= 32 * GC) return;
    int i = t / GC, c = t % GC;
    if (c < 2048) {
        int cc = c >> 5, o = c & 31;
        M[t] = w3[cc * 1024 + i * 32 + o];
    } else {
        M[t] = b3[i * 32 + (c - 2048)];
    }
}

// ---------------- edge MLP: ea(E x 6) -> K(E x 64), permuted order ----------------

__global__ __launch_bounds__(256) void k_mlp(const float* __restrict__ ea, int E,
        const float* __restrict__ w1, const float* __restrict__ b1,
        const float* __restrict__ w2, const float* __restrict__ b2,
        const int* __restrict__ perm, float* __restrict__ K) {
    __shared__ float sw1[KIN * KW];
    __shared__ float sw2[KW * KW];
    __shared__ float sb1[KW];
    __shared__ float sb2[KW];
    for (int i = threadIdx.x; i < KIN * KW; i += 256) sw1[i] = w1[i];
    for (int i = threadIdx.x; i < KW * KW; i += 256)  sw2[i] = w2[i];
    if (threadIdx.x < KW) { sb1[threadIdx.x] = b1[threadIdx.x]; sb2[threadIdx.x] = b2[threadIdx.x]; }
    __syncthreads();
    int e = blockIdx.x * 256 + threadIdx.x;
    if (e >= E) return;
    int eo = perm ? perm[e] : e;
    float a0 = ea[(size_t)eo * KIN + 0];
    float a1 = ea[(size_t)eo * KIN + 1];
    float a2 = ea[(size_t)eo * KIN + 2];
    float a3 = ea[(size_t)eo * KIN + 3];
    float a4 = ea[(size_t)eo * KIN + 4];
    float a5 = ea[(size_t)eo * KIN + 5];
    float t[KW];
#pragma unroll
    for (int j = 0; j < KW; j++) {
        float s = sb1[j];
        s += a0 * sw1[0 * KW + j];
        s += a1 * sw1[1 * KW + j];
        s += a2 * sw1[2 * KW + j];
        s += a3 * sw1[3 * KW + j];
        s += a4 * sw1[4 * KW + j];
        s += a5 * sw1[5 * KW + j];
        t[j] = fmaxf(s, 0.0f);
    }
#pragma unroll
    for (int h = 0; h < 2; h++) {
        int j0 = h * 32;
        float4 acc[8];
#pragma unroll
        for (int jj = 0; jj < 8; jj++)
            acc[jj] = *(const float4*)&sb2[j0 + jj * 4];
#pragma unroll
        for (int c = 0; c < KW; c++) {
            float tc = t[c];
#pragma unroll
            for (int jj = 0; jj < 8; jj++) {
                float4 w = *(const float4*)&sw2[c * KW + j0 + jj * 4];
                acc[jj].x += tc * w.x; acc[jj].y += tc * w.y;
                acc[jj].z += tc * w.z; acc[jj].w += tc * w.w;
            }
        }
#pragma unroll
        for (int jj = 0; jj < 8; jj++) {
            float4 r = acc[jj];
            r.x = fmaxf(r.x, 0.f); r.y = fmaxf(r.y, 0.f);
            r.z = fmaxf(r.z, 0.f); r.w = fmaxf(r.w, 0.f);
            *(float4*)&K[(size_t)e * KW + j0 + jj * 4] = r;
        }
    }
}

// ---------------- fused per-depth sweep, dual-graph, NB2=16 ----------------
// One dispatch handles BOTH graphs: blocks [0, nblkA) -> main, rest -> boundary.
// Phase A: G rows (16 x 2080) in LDS; one thread owns one col-quad for ALL 16
// rows (64 acc VGPRs, each M quad loaded exactly once per block).
// Phase B: contiguous src-sorted edge range, 64 groups of 8 lanes.

__global__ __launch_bounds__(512, 1) void k_fuse2(
        const int* __restrict__ sA, const int* __restrict__ dAr,
        const int* __restrict__ aoffA, const int* __restrict__ arankA,
        const int* __restrict__ anA, const int* __restrict__ dnaA,
        const float* __restrict__ KA, const float* __restrict__ MA,
        float* __restrict__ aggA,
        const int* __restrict__ sB, const int* __restrict__ dBr,
        const int* __restrict__ aoffB, const int* __restrict__ arankB,
        const int* __restrict__ anB, const int* __restrict__ dnaB,
        const float* __restrict__ KB, const float* __restrict__ MB,
        float* __restrict__ aggB,
        const float* __restrict__ h, int nblkA) {
    __shared__ float sG[NB2 * GROW];   // 133.4 KB
    __shared__ float sHt[32 * NB2];    // [k][r], 2 KB
    const int *src_s, *dst_s, *aoff, *arank, *anodes;
    const float *Ks, *M;
    float* agg;
    int bid, na;
    if ((int)blockIdx.x < nblkA) {
        bid = blockIdx.x; na = dnaA[0];
        src_s = sA; dst_s = dAr; aoff = aoffA; arank = arankA; anodes = anA;
        Ks = KA; M = MA; agg = aggA;
    } else {
        bid = blockIdx.x - nblkA; na = dnaB[0];
        src_s = sB; dst_s = dBr; aoff = aoffB; arank = arankB; anodes = anB;
        Ks = KB; M = MB; agg = aggB;
    }
    int a0 = bid * NB2;
    if (a0 >= na) return;
    int t = threadIdx.x;
    {
        int r = t >> 5, k = t & 31;   // r in 0..15 for 512 threads
        float v = 0.0f;
        if (a0 + r < na) v = h[(size_t)anodes[a0 + r] * WID + k];
        sHt[k * NB2 + r] = v;
    }
    __syncthreads();
    // phase A: pass 0 covers quads 0..511, pass 1 covers 512..519 (bias cols)
#pragma unroll
    for (int pass = 0; pass < 2; pass++) {
        int q = pass * 512 + t;
        if (q < GC / 4) {
            int col = q * 4;
            float4 acc[NB2];
#pragma unroll
            for (int r = 0; r < NB2; r++) acc[r] = make_float4(0.f, 0.f, 0.f, 0.f);
#pragma unroll 4
            for (int k = 0; k < 32; k++) {
                float4 mv = *(const float4*)&M[(size_t)k * GC + col];
                float4 h0v = *(const float4*)&sHt[k * NB2 + 0];
                float4 h1v = *(const float4*)&sHt[k * NB2 + 4];
                float4 h2v = *(const float4*)&sHt[k * NB2 + 8];
                float4 h3v = *(const float4*)&sHt[k * NB2 + 12];
                float hv[NB2] = {h0v.x, h0v.y, h0v.z, h0v.w,
                                 h1v.x, h1v.y, h1v.z, h1v.w,
                                 h2v.x, h2v.y, h2v.z, h2v.w,
                                 h3v.x, h3v.y, h3v.z, h3v.w};
#pragma unroll
                for (int r = 0; r < NB2; r++) {
                    acc[r].x += hv[r] * mv.x; acc[r].y += hv[r] * mv.y;
                    acc[r].z += hv[r] * mv.z; acc[r].w += hv[r] * mv.w;
                }
            }
#pragma unroll
            for (int r = 0; r < NB2; r++)
                *(float4*)&sG[r * GROW + col] = acc[r];
        }
    }
    __syncthreads();
    // phase B: 64 groups of 8 lanes, 1 edge per group per pass
    int a1 = a0 + NB2; if (a1 > na) a1 = na;
    int e_lo = aoff[a0];
    int e_hi = aoff[a1];
    int g = t >> 3;
    int q4 = (t & 7) * 4;
    for (int e = e_lo + g; e < e_hi; e += 64) {
        int row = arank[src_s[e]] - a0;
        int dst = dst_s[e];
        const float* Kr = Ks + (size_t)e * KW;
        int gb = row * GROW;
        float4 v0 = *(const float4*)&sG[gb + 2048 + q4];   // bias-fold column
        float4 v1 = make_float4(0.f, 0.f, 0.f, 0.f);
        float4 v2 = v1, v3 = v1;
#pragma unroll
        for (int c4 = 0; c4 < 16; c4++) {
            float4 kv = *(const float4*)&Kr[c4 * 4];
            float4 g0 = *(const float4*)&sG[gb + (c4 * 4 + 0) * 32 + q4];
            float4 g1 = *(const float4*)&sG[gb + (c4 * 4 + 1) * 32 + q4];
            float4 g2 = *(const float4*)&sG[gb + (c4 * 4 + 2) * 32 + q4];
            float4 g3 = *(const float4*)&sG[gb + (c4 * 4 + 3) * 32 + q4];
            v0.x += kv.x * g0.x; v0.y += kv.x * g0.y; v0.z += kv.x * g0.z; v0.w += kv.x * g0.w;
            v1.x += kv.y * g1.x; v1.y += kv.y * g1.y; v1.z += kv.y * g1.z; v1.w += kv.y * g1.w;
            v2.x += kv.z * g2.x; v2.y += kv.z * g2.y; v2.z += kv.z * g2.z; v2.w += kv.z * g2.w;
            v3.x += kv.w * g3.x; v3.y += kv.w * g3.y; v3.z += kv.w * g3.z; v3.w += kv.w * g3.w;
        }
        float4 m;
        m.x = v0.x + v1.x + v2.x + v3.x;
        m.y = v0.y + v1.y + v2.y + v3.y;
        m.z = v0.z + v1.z + v2.z + v3.z;
        m.w = v0.w + v1.w + v2.w + v3.w;
        float* ap = agg + (size_t)dst * WID + q4;
        unsafeAtomicAdd(ap + 0, m.x);
        unsafeAtomicAdd(ap + 1, m.y);
        unsafeAtomicAdd(ap + 2, m.z);
        unsafeAtomicAdd(ap + 3, m.w);
    }
}

// ---------------- node update + output ----------------

__global__ __launch_bounds__(256) void k_node(const float* __restrict__ hin,
        float* __restrict__ hout,
        const float* __restrict__ agg1, const float* __restrict__ aggb,
        const float* __restrict__ inv1, const float* __restrict__ invb,
        const float* __restrict__ h0, const float* __restrict__ rs,
        const float* __restrict__ bs) {
    __shared__ float sR[1024];
    __shared__ float sB[32];
    for (int i = threadIdx.x; i < 1024; i += 256) sR[i] = rs[i];
    if (threadIdx.x < 32) sB[threadIdx.x] = bs[threadIdx.x];
    __syncthreads();
    int t = blockIdx.x * 256 + threadIdx.x;
    if (t >= NN * WID) return;
    int n = t >> 5, j = t & 31;
    float s = agg1[t] * inv1[n] + aggb[t] * invb[n] + sB[j];
    const float* hr = hin + (size_t)n * WID;
#pragma unroll
    for (int i = 0; i < 32; i++) s += hr[i] * sR[i * 32 + j];
    hout[t] = fmaxf(s, 0.0f) + h0[t];
}

__global__ void k_fc2(const float* __restrict__ h, const float* __restrict__ w,
                      const float* __restrict__ b, float* __restrict__ out) {
    int n = blockIdx.x * blockDim.x + threadIdx.x;
    if (n >= NN) return;
    const float4* hv = (const float4*)(h + (size_t)n * WID);
    const float4* wv = (const float4*)w;
    float s = b[0];
#pragma unroll
    for (int q = 0; q < 8; q++) {
        float4 a = hv[q], c = wv[q];
        s += a.x * c.x + a.y * c.y + a.z * c.z + a.w * c.w;
    }
    out[n] = s;
}

// ---------------- launch ----------------

extern "C" void kernel_launch(void* const* d_in, const int* in_sizes, int n_in,
                              void* d_out, int out_size, void* d_ws, size_t ws_size,
                              hipStream_t stream) {
    const float* x    = (const float*)d_in[0];
    const int*   ei   = (const int*)d_in[1];
    const float* ea   = (const float*)d_in[2];
    const int*   eib  = (const int*)d_in[3];
    const float* eab  = (const float*)d_in[4];
    const float* fc1w = (const float*)d_in[5];
    const float* fc1b = (const float*)d_in[6];
    const float* fc2w = (const float*)d_in[7];
    const float* fc2b = (const float*)d_in[8];
    const float* k1w1 = (const float*)d_in[9];
    const float* k1b1 = (const float*)d_in[10];
    const float* k1w2 = (const float*)d_in[11];
    const float* k1b2 = (const float*)d_in[12];
    const float* k1w3 = (const float*)d_in[13];
    const float* k1b3 = (const float*)d_in[14];
    const float* root1= (const float*)d_in[15];
    const float* bias1= (const float*)d_in[16];
    const float* k2w1 = (const float*)d_in[17];
    const float* k2b1 = (const float*)d_in[18];
    const float* k2w2 = (const float*)d_in[19];
    const float* k2b2 = (const float*)d_in[20];
    const float* k2w3 = (const float*)d_in[21];
    const float* k2b3 = (const float*)d_in[22];
    const float* root2= (const float*)d_in[23];
    const float* bias2= (const float*)d_in[24];

    float* p = (float*)d_ws;
    auto alloc = [&](size_t nflt) { float* r = p; p += nflt; return r; };
    float* K1   = alloc((size_t)EM * KW);     // sorted (by src) order
    float* Kb   = alloc((size_t)EBN * KW);
    float* h0   = alloc((size_t)NN * WID);
    float* hA   = alloc((size_t)NN * WID);
    float* hB   = alloc((size_t)NN * WID);
    float* agg1 = alloc((size_t)NN * WID);    // agg1+aggb contiguous: single memset
    float* aggb = alloc((size_t)NN * WID);
    float* inv1 = alloc(NN);
    float* invb = alloc(NN);
    float* rs   = alloc(1024);
    float* bs   = alloc(32);
    int*   cnt1 = (int*)alloc(NN);   // cnt1,cntb,cs1,csb contiguous: single memset
    int*   cntb = (int*)alloc(NN);
    int*   cs1  = (int*)alloc(NN);
    int*   csb  = (int*)alloc(NN);
    int*   cur1 = (int*)alloc(NN);
    int*   curb = (int*)alloc(NN);
    int*   arank1 = (int*)alloc(NN);
    int*   arankb = (int*)alloc(NN);
    int*   anodes1= (int*)alloc(NN);
    int*   anodesb= (int*)alloc(NN);
    int*   aoff1  = (int*)alloc(NN + 1);
    int*   aoffb  = (int*)alloc(NN + 1);
    int*   dna1   = (int*)alloc(1);
    int*   dnab   = (int*)alloc(1);
    int*   perm1= (int*)alloc(EM);
    int*   permb= (int*)alloc(EBN);
    int*   srcs1= (int*)alloc(EM);
    int*   dsts1= (int*)alloc(EM);
    int*   srcsb= (int*)alloc(EBN);
    int*   dstsb= (int*)alloc(EBN);
    float* M1   = alloc(32 * GC);
    float* M2   = alloc(32 * GC);

    hipMemsetAsync(cnt1, 0, 4 * NN * sizeof(int), stream);
    k_prep<<<1, 1024, 0, stream>>>(root1, bias1, root2, bias2, rs, bs);
    k_h0<<<(NN * WID + 255) / 256, 256, 0, stream>>>(x, fc1w, fc1b, h0, hA);
    k_count<<<(EM + 255) / 256, 256, 0, stream>>>(ei + EM, EM, cnt1);     // dst counts
    k_count<<<(EBN + 255) / 256, 256, 0, stream>>>(eib + EBN, EBN, cntb);
    k_inv<<<(NN + 255) / 256, 256, 0, stream>>>(cnt1, inv1, NN);
    k_inv<<<(NN + 255) / 256, 256, 0, stream>>>(cntb, invb, NN);
    k_count<<<(EM + 255) / 256, 256, 0, stream>>>(ei, EM, cs1);           // src counts
    k_count<<<(EBN + 255) / 256, 256, 0, stream>>>(eib, EBN, csb);
    k_scan2<<<1, 1024, 0, stream>>>(cs1, cur1, arank1, anodes1, aoff1, dna1, NN, EM);
    k_scan2<<<1, 1024, 0, stream>>>(csb, curb, arankb, anodesb, aoffb, dnab, NN, EBN);
    k_scatter<<<(EM + 255) / 256, 256, 0, stream>>>(ei, EM, cur1, perm1);
    k_scatter<<<(EBN + 255) / 256, 256, 0, stream>>>(eib, EBN, curb, permb);
    k_permidx<<<(EM + 255) / 256, 256, 0, stream>>>(ei, EM, perm1, srcs1, dsts1);
    k_permidx<<<(EBN + 255) / 256, 256, 0, stream>>>(eib, EBN, permb, srcsb, dstsb);
    k_mlp<<<(EM + 255) / 256, 256, 0, stream>>>(ea, EM, k1w1, k1b1, k1w2, k1b2, perm1, K1);
    k_mlp<<<(EBN + 255) / 256, 256, 0, stream>>>(eab, EBN, k2w1, k2b1, k2w2, k2b2, permb, Kb);
    k_permM<<<(32 * GC + 255) / 256, 256, 0, stream>>>(k1w3, k1b3, M1);
    k_permM<<<(32 * GC + 255) / 256, 256, 0, stream>>>(k2w3, k2b3, M2);

    const float* hin = hA;
    float* hout = hB;
    int nblkA = (NN + NB2 - 1) / NB2;           // 1250
    int fgrid = nblkA * 2;                      // main + boundary halves
    for (int d = 0; d < NDEPTH; d++) {
        hipMemsetAsync(agg1, 0, (size_t)2 * NN * WID * sizeof(float), stream);
        k_fuse2<<<fgrid, 512, 0, stream>>>(srcs1, dsts1, aoff1, arank1, anodes1,
                                           dna1, K1, M1, agg1,
                                           srcsb, dstsb, aoffb, arankb, anodesb,
                                           dnab, Kb, M2, aggb,
                                           hin, nblkA);
        k_node<<<(NN * WID + 255) / 256, 256, 0, stream>>>(hin, hout, agg1, aggb,
                                                           inv1, invb, h0, rs, bs);
        float* tmp = (float*)hin; hin = hout; hout = tmp;
    }
    k_fc2<<<(NN + 255) / 256, 256, 0, stream>>>(hin, fc2w, fc2b, (float*)d_out);
}

// Round 8
// 785.615 us; speedup vs baseline: 11.2649x; 1.0216x over previous
//
#include <hip/hip_runtime.h>
#include <cstdint>
#include <cstddef>

#define NN    20000
#define EM    100000
#define EBN   20000
#define WID   32
#define KW    64
#define KIN   6
#define NDEPTH 4
#define GC    2080   // 64*32 kernel cols + 32 bias cols
#define NB2   16     // nodes per fuse-block
#define GROW  2084   // padded LDS row

// ---------------- small setup kernels ----------------

__global__ void k_prep(const float* __restrict__ r1, const float* __restrict__ b1,
                       const float* __restrict__ r2, const float* __restrict__ b2,
                       float* __restrict__ rs, float* __restrict__ bs) {
    int i = threadIdx.x;
    if (i < 1024) rs[i] = r1[i] + r2[i];
    if (i < 32)   bs[i] = b1[i] + b2[i];
}

__global__ void k_h0(const float* __restrict__ x, const float* __restrict__ fc1w,
                     const float* __restrict__ fc1b, float* __restrict__ h0,
                     float* __restrict__ h) {
    int t = blockIdx.x * blockDim.x + threadIdx.x;
    if (t >= NN * WID) return;
    int node = t >> 5, j = t & 31;
    float v = x[node] * fc1w[j] + fc1b[j];
    h0[t] = v; h[t] = v;
}

__global__ void k_count(const int* __restrict__ idx, int E, int* __restrict__ cnt) {
    int e = blockIdx.x * blockDim.x + threadIdx.x;
    if (e < E) atomicAdd(&cnt[idx[e]], 1);
}

__global__ void k_inv(const int* __restrict__ cnt, float* __restrict__ inv, int n) {
    int i = blockIdx.x * blockDim.x + threadIdx.x;
    if (i < n) {
        int c = cnt[i]; if (c < 1) c = 1;
        inv[i] = 1.0f / (float)c;
    }
}

// combined scan over src-counts: edge-offset cursor (cur), active-node rank
// (arank), compacted active list (anodes), active CSR (aoff, aoff[na]=E), na.
__global__ __launch_bounds__(1024) void k_scan2(const int* __restrict__ cnt,
        int* __restrict__ cur, int* __restrict__ arank, int* __restrict__ anodes,
        int* __restrict__ aoff, int* __restrict__ dna, int n, int E) {
    __shared__ int part[1024];
    __shared__ int partf[1024];
    int t = threadIdx.x;
    int per = (n + 1023) / 1024;
    int base = t * per;
    int s = 0, f = 0;
    for (int i = 0; i < per; i++) {
        int idx = base + i;
        if (idx < n) { int c = cnt[idx]; s += c; f += (c > 0) ? 1 : 0; }
    }
    part[t] = s; partf[t] = f;
    __syncthreads();
    for (int od = 1; od < 1024; od <<= 1) {
        int v  = (t >= od) ? part[t - od] : 0;
        int vf = (t >= od) ? partf[t - od] : 0;
        __syncthreads();
        part[t] += v; partf[t] += vf;
        __syncthreads();
    }
    int run  = (t > 0) ? part[t - 1] : 0;
    int runf = (t > 0) ? partf[t - 1] : 0;
    for (int i = 0; i < per; i++) {
        int idx = base + i;
        if (idx < n) {
            int c = cnt[idx];
            cur[idx] = run;
            arank[idx] = runf;
            if (c > 0) { anodes[runf] = idx; aoff[runf] = run; runf++; }
            run += c;
        }
    }
    if (t == 1023) { dna[0] = partf[1023]; aoff[partf[1023]] = E; }
}

__global__ void k_scatter(const int* __restrict__ src, int E,
                          int* __restrict__ cur, int* __restrict__ perm) {
    int e = blockIdx.x * blockDim.x + threadIdx.x;
    if (e < E) { int p = atomicAdd(&cur[src[e]], 1); perm[p] = e; }
}

__global__ void k_permidx(const int* __restrict__ ei, int E,
                          const int* __restrict__ perm,
                          int* __restrict__ src_s, int* __restrict__ dst_s) {
    int i = blockIdx.x * blockDim.x + threadIdx.x;
    if (i >= E) return;
    int e = perm[i];
    src_s[i] = ei[e];
    dst_s[i] = ei[E + e];
}

// M[i][c*32+o] = w3[c][i*32+o] (c<64); M[i][2048+o] = b3[i*32+o]
__global__ void k_permM(const float* __restrict__ w3, const float* __restrict__ b3,
                        float* __restrict__ M) {
    int t = blockIdx.x * blockDim.x + threadIdx.x;
    if (t >= 32 * GC) return;
    int i = t / GC, c = t % GC;
    if (c < 2048) {
        int cc = c >> 5, o = c & 31;
        M[t] = w3[cc * 1024 + i * 32 + o];
    } else {
        M[t] = b3[i * 32 + (c - 2048)];
    }
}

// ---------------- edge MLP: ea(E x 6) -> K(E x 64), permuted order ----------------

__global__ __launch_bounds__(256) void k_mlp(const float* __restrict__ ea, int E,
        const float* __restrict__ w1, const float* __restrict__ b1,
        const float* __restrict__ w2, const float* __restrict__ b2,
        const int* __restrict__ perm, float* __restrict__ K) {
    __shared__ float sw1[KIN * KW];
    __shared__ float sw2[KW * KW];
    __shared__ float sb1[KW];
    __shared__ float sb2[KW];
    for (int i = threadIdx.x; i < KIN * KW; i += 256) sw1[i] = w1[i];
    for (int i = threadIdx.x; i < KW * KW; i += 256)  sw2[i] = w2[i];
    if (threadIdx.x < KW) { sb1[threadIdx.x] = b1[threadIdx.x]; sb2[threadIdx.x] = b2[threadIdx.x]; }
    __syncthreads();
    int e = blockIdx.x * 256 + threadIdx.x;
    if (e >= E) return;
    int eo = perm ? perm[e] : e;
    float a0 = ea[(size_t)eo * KIN + 0];
    float a1 = ea[(size_t)eo * KIN + 1];
    float a2 = ea[(size_t)eo * KIN + 2];
    float a3 = ea[(size_t)eo * KIN + 3];
    float a4 = ea[(size_t)eo * KIN + 4];
    float a5 = ea[(size_t)eo * KIN + 5];
    float t[KW];
#pragma unroll
    for (int j = 0; j < KW; j++) {
        float s = sb1[j];
        s += a0 * sw1[0 * KW + j];
        s += a1 * sw1[1 * KW + j];
        s += a2 * sw1[2 * KW + j];
        s += a3 * sw1[3 * KW + j];
        s += a4 * sw1[4 * KW + j];
        s += a5 * sw1[5 * KW + j];
        t[j] = fmaxf(s, 0.0f);
    }
#pragma unroll
    for (int h = 0; h < 2; h++) {
        int j0 = h * 32;
        float4 acc[8];
#pragma unroll
        for (int jj = 0; jj < 8; jj++)
            acc[jj] = *(const float4*)&sb2[j0 + jj * 4];
#pragma unroll
        for (int c = 0; c < KW; c++) {
            float tc = t[c];
#pragma unroll
            for (int jj = 0; jj < 8; jj++) {
                float4 w = *(const float4*)&sw2[c * KW + j0 + jj * 4];
                acc[jj].x += tc * w.x; acc[jj].y += tc * w.y;
                acc[jj].z += tc * w.z; acc[jj].w += tc * w.w;
            }
        }
#pragma unroll
        for (int jj = 0; jj < 8; jj++) {
            float4 r = acc[jj];
            r.x = fmaxf(r.x, 0.f); r.y = fmaxf(r.y, 0.f);
            r.z = fmaxf(r.z, 0.f); r.w = fmaxf(r.w, 0.f);
            *(float4*)&K[(size_t)e * KW + j0 + jj * 4] = r;
        }
    }
}

// ---------------- fused per-depth sweep, dual-graph, NB2=16, 1024 threads ----------------
// One dispatch handles BOTH graphs: blocks [0, nblkA) -> main, rest -> boundary.
// Phase A: G rows (16 x 2080) in LDS; one thread owns one float2 col-pair for
// ALL 16 rows (32 acc VGPRs); all 16 waves active; M read once per block.
// Phase B: contiguous src-sorted edge range, 128 groups of 8 lanes.

__global__ __launch_bounds__(1024, 1) void k_fuse2(
        const int* __restrict__ sA, const int* __restrict__ dAr,
        const int* __restrict__ aoffA, const int* __restrict__ arankA,
        const int* __restrict__ anA, const int* __restrict__ dnaA,
        const float* __restrict__ KA, const float* __restrict__ MA,
        float* __restrict__ aggA,
        const int* __restrict__ sB, const int* __restrict__ dBr,
        const int* __restrict__ aoffB, const int* __restrict__ arankB,
        const int* __restrict__ anB, const int* __restrict__ dnaB,
        const float* __restrict__ KB, const float* __restrict__ MB,
        float* __restrict__ aggB,
        const float* __restrict__ h, int nblkA) {
    __shared__ float sG[NB2 * GROW];   // 133.4 KB
    __shared__ float sHt[32 * NB2];    // [k][r], 2 KB
    const int *src_s, *dst_s, *aoff, *arank, *anodes;
    const float *Ks, *M;
    float* agg;
    int bid, na;
    if ((int)blockIdx.x < nblkA) {
        bid = blockIdx.x; na = dnaA[0];
        src_s = sA; dst_s = dAr; aoff = aoffA; arank = arankA; anodes = anA;
        Ks = KA; M = MA; agg = aggA;
    } else {
        bid = blockIdx.x - nblkA; na = dnaB[0];
        src_s = sB; dst_s = dBr; aoff = aoffB; arank = arankB; anodes = anB;
        Ks = KB; M = MB; agg = aggB;
    }
    int a0 = bid * NB2;
    if (a0 >= na) return;
    int t = threadIdx.x;
    if (t < 512) {
        int r = t >> 5, k = t & 31;   // r in 0..15
        float v = 0.0f;
        if (a0 + r < na) v = h[(size_t)anodes[a0 + r] * WID + k];
        sHt[k * NB2 + r] = v;
    }
    __syncthreads();
    // phase A: thread owns col-pair p (and p+1024 leftover); 1040 pairs total
    for (int p = t; p < GC / 2; p += 1024) {
        int col = p * 2;
        float2 acc[NB2];
#pragma unroll
        for (int r = 0; r < NB2; r++) { acc[r].x = 0.f; acc[r].y = 0.f; }
#pragma unroll 4
        for (int k = 0; k < 32; k++) {
            float2 mv = *(const float2*)&M[(size_t)k * GC + col];
            float4 h0v = *(const float4*)&sHt[k * NB2 + 0];
            float4 h1v = *(const float4*)&sHt[k * NB2 + 4];
            float4 h2v = *(const float4*)&sHt[k * NB2 + 8];
            float4 h3v = *(const float4*)&sHt[k * NB2 + 12];
            float hv[NB2] = {h0v.x, h0v.y, h0v.z, h0v.w,
                             h1v.x, h1v.y, h1v.z, h1v.w,
                             h2v.x, h2v.y, h2v.z, h2v.w,
                             h3v.x, h3v.y, h3v.z, h3v.w};
#pragma unroll
            for (int r = 0; r < NB2; r++) {
                acc[r].x += hv[r] * mv.x;
                acc[r].y += hv[r] * mv.y;
            }
        }
#pragma unroll
        for (int r = 0; r < NB2; r++)
            *(float2*)&sG[r * GROW + col] = acc[r];
    }
    __syncthreads();
    // phase B: 128 groups of 8 lanes, 1 edge per group per pass
    int a1 = a0 + NB2; if (a1 > na) a1 = na;
    int e_lo = aoff[a0];
    int e_hi = aoff[a1];
    int g = t >> 3;
    int q4 = (t & 7) * 4;
    for (int e = e_lo + g; e < e_hi; e += 128) {
        int row = arank[src_s[e]] - a0;
        int dst = dst_s[e];
        const float* Kr = Ks + (size_t)e * KW;
        int gb = row * GROW;
        float4 v0 = *(const float4*)&sG[gb + 2048 + q4];   // bias-fold column
        float4 v1 = make_float4(0.f, 0.f, 0.f, 0.f);
        float4 v2 = v1, v3 = v1;
#pragma unroll
        for (int c4 = 0; c4 < 16; c4++) {
            float4 kv = *(const float4*)&Kr[c4 * 4];
            float4 g0 = *(const float4*)&sG[gb + (c4 * 4 + 0) * 32 + q4];
            float4 g1 = *(const float4*)&sG[gb + (c4 * 4 + 1) * 32 + q4];
            float4 g2 = *(const float4*)&sG[gb + (c4 * 4 + 2) * 32 + q4];
            float4 g3 = *(const float4*)&sG[gb + (c4 * 4 + 3) * 32 + q4];
            v0.x += kv.x * g0.x; v0.y += kv.x * g0.y; v0.z += kv.x * g0.z; v0.w += kv.x * g0.w;
            v1.x += kv.y * g1.x; v1.y += kv.y * g1.y; v1.z += kv.y * g1.z; v1.w += kv.y * g1.w;
            v2.x += kv.z * g2.x; v2.y += kv.z * g2.y; v2.z += kv.z * g2.z; v2.w += kv.z * g2.w;
            v3.x += kv.w * g3.x; v3.y += kv.w * g3.y; v3.z += kv.w * g3.z; v3.w += kv.w * g3.w;
        }
        float4 m;
        m.x = v0.x + v1.x + v2.x + v3.x;
        m.y = v0.y + v1.y + v2.y + v3.y;
        m.z = v0.z + v1.z + v2.z + v3.z;
        m.w = v0.w + v1.w + v2.w + v3.w;
        float* ap = agg + (size_t)dst * WID + q4;
        unsafeAtomicAdd(ap + 0, m.x);
        unsafeAtomicAdd(ap + 1, m.y);
        unsafeAtomicAdd(ap + 2, m.z);
        unsafeAtomicAdd(ap + 3, m.w);
    }
}

// ---------------- node update + output ----------------

__global__ __launch_bounds__(256) void k_node(const float* __restrict__ hin,
        float* __restrict__ hout,
        const float* __restrict__ agg1, const float* __restrict__ aggb,
        const float* __restrict__ inv1, const float* __restrict__ invb,
        const float* __restrict__ h0, const float* __restrict__ rs,
        const float* __restrict__ bs) {
    __shared__ float sR[1024];
    __shared__ float sB[32];
    for (int i = threadIdx.x; i < 1024; i += 256) sR[i] = rs[i];
    if (threadIdx.x < 32) sB[threadIdx.x] = bs[threadIdx.x];
    __syncthreads();
    int t = blockIdx.x * 256 + threadIdx.x;
    if (t >= NN * WID) return;
    int n = t >> 5, j = t & 31;
    float s = agg1[t] * inv1[n] + aggb[t] * invb[n] + sB[j];
    const float* hr = hin + (size_t)n * WID;
#pragma unroll
    for (int i = 0; i < 32; i++) s += hr[i] * sR[i * 32 + j];
    hout[t] = fmaxf(s, 0.0f) + h0[t];
}

__global__ void k_fc2(const float* __restrict__ h, const float* __restrict__ w,
                      const float* __restrict__ b, float* __restrict__ out) {
    int n = blockIdx.x * blockDim.x + threadIdx.x;
    if (n >= NN) return;
    const float4* hv = (const float4*)(h + (size_t)n * WID);
    const float4* wv = (const float4*)w;
    float s = b[0];
#pragma unroll
    for (int q = 0; q < 8; q++) {
        float4 a = hv[q], c = wv[q];
        s += a.x * c.x + a.y * c.y + a.z * c.z + a.w * c.w;
    }
    out[n] = s;
}

// ---------------- launch ----------------

extern "C" void kernel_launch(void* const* d_in, const int* in_sizes, int n_in,
                              void* d_out, int out_size, void* d_ws, size_t ws_size,
                              hipStream_t stream) {
    const float* x    = (const float*)d_in[0];
    const int*   ei   = (const int*)d_in[1];
    const float* ea   = (const float*)d_in[2];
    const int*   eib  = (const int*)d_in[3];
    const float* eab  = (const float*)d_in[4];
    const float* fc1w = (const float*)d_in[5];
    const float* fc1b = (const float*)d_in[6];
    const float* fc2w = (const float*)d_in[7];
    const float* fc2b = (const float*)d_in[8];
    const float* k1w1 = (const float*)d_in[9];
    const float* k1b1 = (const float*)d_in[10];
    const float* k1w2 = (const float*)d_in[11];
    const float* k1b2 = (const float*)d_in[12];
    const float* k1w3 = (const float*)d_in[13];
    const float* k1b3 = (const float*)d_in[14];
    const float* root1= (const float*)d_in[15];
    const float* bias1= (const float*)d_in[16];
    const float* k2w1 = (const float*)d_in[17];
    const float* k2b1 = (const float*)d_in[18];
    const float* k2w2 = (const float*)d_in[19];
    const float* k2b2 = (const float*)d_in[20];
    const float* k2w3 = (const float*)d_in[21];
    const float* k2b3 = (const float*)d_in[22];
    const float* root2= (const float*)d_in[23];
    const float* bias2= (const float*)d_in[24];

    float* p = (float*)d_ws;
    auto alloc = [&](size_t nflt) { float* r = p; p += nflt; return r; };
    float* K1   = alloc((size_t)EM * KW);     // sorted (by src) order
    float* Kb   = alloc((size_t)EBN * KW);
    float* h0   = alloc((size_t)NN * WID);
    float* hA   = alloc((size_t)NN * WID);
    float* hB   = alloc((size_t)NN * WID);
    float* agg1 = alloc((size_t)NN * WID);    // agg1+aggb contiguous: single memset
    float* aggb = alloc((size_t)NN * WID);
    float* inv1 = alloc(NN);
    float* invb = alloc(NN);
    float* rs   = alloc(1024);
    float* bs   = alloc(32);
    int*   cnt1 = (int*)alloc(NN);   // cnt1,cntb,cs1,csb contiguous: single memset
    int*   cntb = (int*)alloc(NN);
    int*   cs1  = (int*)alloc(NN);
    int*   csb  = (int*)alloc(NN);
    int*   cur1 = (int*)alloc(NN);
    int*   curb = (int*)alloc(NN);
    int*   arank1 = (int*)alloc(NN);
    int*   arankb = (int*)alloc(NN);
    int*   anodes1= (int*)alloc(NN);
    int*   anodesb= (int*)alloc(NN);
    int*   aoff1  = (int*)alloc(NN + 1);
    int*   aoffb  = (int*)alloc(NN + 1);
    int*   dna1   = (int*)alloc(1);
    int*   dnab   = (int*)alloc(1);
    int*   perm1= (int*)alloc(EM);
    int*   permb= (int*)alloc(EBN);
    int*   srcs1= (int*)alloc(EM);
    int*   dsts1= (int*)alloc(EM);
    int*   srcsb= (int*)alloc(EBN);
    int*   dstsb= (int*)alloc(EBN);
    float* M1   = alloc(32 * GC);
    float* M2   = alloc(32 * GC);

    hipMemsetAsync(cnt1, 0, 4 * NN * sizeof(int), stream);
    k_prep<<<1, 1024, 0, stream>>>(root1, bias1, root2, bias2, rs, bs);
    k_h0<<<(NN * WID + 255) / 256, 256, 0, stream>>>(x, fc1w, fc1b, h0, hA);
    k_count<<<(EM + 255) / 256, 256, 0, stream>>>(ei + EM, EM, cnt1);     // dst counts
    k_count<<<(EBN + 255) / 256, 256, 0, stream>>>(eib + EBN, EBN, cntb);
    k_inv<<<(NN + 255) / 256, 256, 0, stream>>>(cnt1, inv1, NN);
    k_inv<<<(NN + 255) / 256, 256, 0, stream>>>(cntb, invb, NN);
    k_count<<<(EM + 255) / 256, 256, 0, stream>>>(ei, EM, cs1);           // src counts
    k_count<<<(EBN + 255) / 256, 256, 0, stream>>>(eib, EBN, csb);
    k_scan2<<<1, 1024, 0, stream>>>(cs1, cur1, arank1, anodes1, aoff1, dna1, NN, EM);
    k_scan2<<<1, 1024, 0, stream>>>(csb, curb, arankb, anodesb, aoffb, dnab, NN, EBN);
    k_scatter<<<(EM + 255) / 256, 256, 0, stream>>>(ei, EM, cur1, perm1);
    k_scatter<<<(EBN + 255) / 256, 256, 0, stream>>>(eib, EBN, curb, permb);
    k_permidx<<<(EM + 255) / 256, 256, 0, stream>>>(ei, EM, perm1, srcs1, dsts1);
    k_permidx<<<(EBN + 255) / 256, 256, 0, stream>>>(eib, EBN, permb, srcsb, dstsb);
    k_mlp<<<(EM + 255) / 256, 256, 0, stream>>>(ea, EM, k1w1, k1b1, k1w2, k1b2, perm1, K1);
    k_mlp<<<(EBN + 255) / 256, 256, 0, stream>>>(eab, EBN, k2w1, k2b1, k2w2, k2b2, permb, Kb);
    k_permM<<<(32 * GC + 255) / 256, 256, 0, stream>>>(k1w3, k1b3, M1);
    k_permM<<<(32 * GC + 255) / 256, 256, 0, stream>>>(k2w3, k2b3, M2);

    const float* hin = hA;
    float* hout = hB;
    int nblkA = (NN + NB2 - 1) / NB2;           // 1250
    int fgrid = nblkA * 2;                      // main + boundary halves
    for (int d = 0; d < NDEPTH; d++) {
        hipMemsetAsync(agg1, 0, (size_t)2 * NN * WID * sizeof(float), stream);
        k_fuse2<<<fgrid, 1024, 0, stream>>>(srcs1, dsts1, aoff1, arank1, anodes1,
                                            dna1, K1, M1, agg1,
                                            srcsb, dstsb, aoffb, arankb, anodesb,
                                            dnab, Kb, M2, aggb,
                                            hin, nblkA);
        k_node<<<(NN * WID + 255) / 256, 256, 0, stream>>>(hin, hout, agg1, aggb,
                                                           inv1, invb, h0, rs, bs);
        float* tmp = (float*)hin; hin = hout; hout = tmp;
    }
    k_fc2<<<(NN + 255) / 256, 256, 0, stream>>>(hin, fc2w, fc2b, (float*)d_out);
}

// Round 9
// 610.114 us; speedup vs baseline: 14.5053x; 1.2877x over previous
//
#include <hip/hip_runtime.h>
#include <cstdint>
#include <cstddef>

#define NN    20000
#define EM    100000
#define EBN   20000
#define WID   32
#define KW    64
#define KIN   6
#define NDEPTH 4
#define GC    2080   // 64*32 kernel cols + 32 bias cols
#define NBL   8      // nodes per fuse-block
#define GR    2084   // padded LDS row
#define NQ    520    // GC/4 col-quads
#define TPB_F 576    // 9 waves

// ---------------- h init: hA = x @ fc1w + fc1b ----------------

__global__ void k_h0(const float* __restrict__ x, const float* __restrict__ fc1w,
                     const float* __restrict__ fc1b, float* __restrict__ h) {
    int t = blockIdx.x * blockDim.x + threadIdx.x;
    if (t >= NN * WID) return;
    int node = t >> 5, j = t & 31;
    h[t] = x[node] * fc1w[j] + fc1b[j];
}

// ---------------- merged degree counts (src+dst, both graphs) ----------------

__global__ void k_count4(const int* __restrict__ ei, const int* __restrict__ eib,
                         int* __restrict__ cs1, int* __restrict__ cnt1,
                         int* __restrict__ csb, int* __restrict__ cntb) {
    int t = blockIdx.x * blockDim.x + threadIdx.x;
    if (t < EM) atomicAdd(&cs1[ei[t]], 1);
    else if (t < 2 * EM) atomicAdd(&cnt1[ei[t]], 1);           // ei[EM..2EM) = dst
    else if (t < 2 * EM + EBN) atomicAdd(&csb[eib[t - 2 * EM]], 1);
    else if (t < 2 * EM + 2 * EBN) atomicAdd(&cntb[eib[t - 2 * EM]], 1);
}

__global__ void k_inv2(const int* __restrict__ cnt1, float* __restrict__ inv1,
                       const int* __restrict__ cntb, float* __restrict__ invb) {
    int i = blockIdx.x * blockDim.x + threadIdx.x;
    if (i < NN) {
        int c = cnt1[i]; if (c < 1) c = 1;
        inv1[i] = 1.0f / (float)c;
    } else if (i < 2 * NN) {
        int c = cntb[i - NN]; if (c < 1) c = 1;
        invb[i - NN] = 1.0f / (float)c;
    }
}

// ---------------- dual scan (block 0: main, block 1: boundary) ----------------
// exclusive scan of src-counts -> cur (scatter cursor), arank (active rank),
// anodes (compacted actives), aoff (active CSR, aoff[na]=E), dna = na.

__global__ __launch_bounds__(1024) void k_scan3(
        const int* __restrict__ csA, int* __restrict__ curA, int* __restrict__ arankA,
        int* __restrict__ anodesA, int* __restrict__ aoffA, int* __restrict__ dnaA, int EA,
        const int* __restrict__ csB, int* __restrict__ curB, int* __restrict__ arankB,
        int* __restrict__ anodesB, int* __restrict__ aoffB, int* __restrict__ dnaB, int EB) {
    __shared__ int part[1024];
    __shared__ int partf[1024];
    const int* cnt; int *cur, *arank, *anodes, *aoff, *dna; int E;
    if (blockIdx.x == 0) { cnt = csA; cur = curA; arank = arankA; anodes = anodesA; aoff = aoffA; dna = dnaA; E = EA; }
    else                 { cnt = csB; cur = curB; arank = arankB; anodes = anodesB; aoff = aoffB; dna = dnaB; E = EB; }
    int t = threadIdx.x;
    int per = (NN + 1023) / 1024;
    int base = t * per;
    int s = 0, f = 0;
    for (int i = 0; i < per; i++) {
        int idx = base + i;
        if (idx < NN) { int c = cnt[idx]; s += c; f += (c > 0) ? 1 : 0; }
    }
    part[t] = s; partf[t] = f;
    __syncthreads();
    for (int od = 1; od < 1024; od <<= 1) {
        int v  = (t >= od) ? part[t - od] : 0;
        int vf = (t >= od) ? partf[t - od] : 0;
        __syncthreads();
        part[t] += v; partf[t] += vf;
        __syncthreads();
    }
    int run  = (t > 0) ? part[t - 1] : 0;
    int runf = (t > 0) ? partf[t - 1] : 0;
    for (int i = 0; i < per; i++) {
        int idx = base + i;
        if (idx < NN) {
            int c = cnt[idx];
            cur[idx] = run;
            arank[idx] = runf;
            if (c > 0) { anodes[runf] = idx; aoff[runf] = run; runf++; }
            run += c;
        }
    }
    if (t == 1023) { dna[0] = partf[1023]; aoff[partf[1023]] = E; }
}

// ---------------- merged scatter + index build ----------------

__global__ void k_scatter3(const int* __restrict__ ei, int* __restrict__ cur1,
                           int* __restrict__ perm1, const int* __restrict__ eib,
                           int* __restrict__ curb, int* __restrict__ permb) {
    int t = blockIdx.x * blockDim.x + threadIdx.x;
    if (t < EM) { int p = atomicAdd(&cur1[ei[t]], 1); perm1[p] = t; }
    else if (t < EM + EBN) {
        int e = t - EM;
        int p = atomicAdd(&curb[eib[e]], 1); permb[p] = e;
    }
}

// rk_s[i] = rank of src of sorted edge i; dst_s[i] = dst of sorted edge i
__global__ void k_permidx3(const int* __restrict__ ei, const int* __restrict__ perm1,
                           const int* __restrict__ arank1, int* __restrict__ rk1,
                           int* __restrict__ dst1,
                           const int* __restrict__ eib, const int* __restrict__ permb,
                           const int* __restrict__ arankb, int* __restrict__ rkb,
                           int* __restrict__ dstb) {
    int t = blockIdx.x * blockDim.x + threadIdx.x;
    if (t < EM) {
        int e = perm1[t];
        rk1[t] = arank1[ei[e]];
        dst1[t] = ei[EM + e];
    } else if (t < EM + EBN) {
        int i = t - EM;
        int e = permb[i];
        rkb[i] = arankb[eib[e]];
        dstb[i] = eib[EBN + e];
    }
}

// ---------------- M permute (+ root/bias prep folded in) ----------------
// M[i][c*32+o] = w3[c][i*32+o] (c<64); M[i][2048+o] = b3[i*32+o]

__global__ void k_permM3(const float* __restrict__ w3a, const float* __restrict__ b3a,
                         float* __restrict__ M1,
                         const float* __restrict__ w3b, const float* __restrict__ b3b,
                         float* __restrict__ M2,
                         const float* __restrict__ r1, const float* __restrict__ b1,
                         const float* __restrict__ r2, const float* __restrict__ b2,
                         float* __restrict__ rs, float* __restrict__ bs) {
    int t = blockIdx.x * blockDim.x + threadIdx.x;
    if (t < 32 * GC) {
        int i = t / GC, c = t % GC;
        M1[t] = (c < 2048) ? w3a[(c >> 5) * 1024 + i * 32 + (c & 31)]
                           : b3a[i * 32 + (c - 2048)];
    } else if (t < 64 * GC) {
        int u = t - 32 * GC;
        int i = u / GC, c = u % GC;
        M2[u] = (c < 2048) ? w3b[(c >> 5) * 1024 + i * 32 + (c & 31)]
                           : b3b[i * 32 + (c - 2048)];
    } else if (t < 64 * GC + 1024) {
        int i = t - 64 * GC;
        rs[i] = r1[i] + r2[i];
    } else if (t < 64 * GC + 1056) {
        int i = t - 64 * GC - 1024;
        bs[i] = b1[i] + b2[i];
    }
}

// ---------------- merged edge MLP (both graphs), permuted order ----------------

__global__ __launch_bounds__(256) void k_mlp3(
        const float* __restrict__ ea1, const int* __restrict__ perm1,
        const float* __restrict__ w1a, const float* __restrict__ b1a,
        const float* __restrict__ w2a, const float* __restrict__ b2a,
        float* __restrict__ K1,
        const float* __restrict__ ea2, const int* __restrict__ permb,
        const float* __restrict__ w1b, const float* __restrict__ b1b,
        const float* __restrict__ w2b, const float* __restrict__ b2b,
        float* __restrict__ K2, int nmb) {
    __shared__ float sw1[KIN * KW];
    __shared__ float sw2[KW * KW];
    __shared__ float sb1[KW];
    __shared__ float sb2[KW];
    const float *ea, *w1, *b1, *w2, *b2;
    const int* perm;
    float* K;
    int e, E;
    if ((int)blockIdx.x < nmb) {
        ea = ea1; perm = perm1; w1 = w1a; b1 = b1a; w2 = w2a; b2 = b2a; K = K1;
        e = blockIdx.x * 256 + threadIdx.x; E = EM;
    } else {
        ea = ea2; perm = permb; w1 = w1b; b1 = b1b; w2 = w2b; b2 = b2b; K = K2;
        e = (blockIdx.x - nmb) * 256 + threadIdx.x; E = EBN;
    }
    for (int i = threadIdx.x; i < KIN * KW; i += 256) sw1[i] = w1[i];
    for (int i = threadIdx.x; i < KW * KW; i += 256)  sw2[i] = w2[i];
    if (threadIdx.x < KW) { sb1[threadIdx.x] = b1[threadIdx.x]; sb2[threadIdx.x] = b2[threadIdx.x]; }
    __syncthreads();
    if (e >= E) return;
    int eo = perm[e];
    float a0 = ea[(size_t)eo * KIN + 0];
    float a1 = ea[(size_t)eo * KIN + 1];
    float a2 = ea[(size_t)eo * KIN + 2];
    float a3 = ea[(size_t)eo * KIN + 3];
    float a4 = ea[(size_t)eo * KIN + 4];
    float a5 = ea[(size_t)eo * KIN + 5];
    float t[KW];
#pragma unroll
    for (int j = 0; j < KW; j++) {
        float s = sb1[j];
        s += a0 * sw1[0 * KW + j];
        s += a1 * sw1[1 * KW + j];
        s += a2 * sw1[2 * KW + j];
        s += a3 * sw1[3 * KW + j];
        s += a4 * sw1[4 * KW + j];
        s += a5 * sw1[5 * KW + j];
        t[j] = fmaxf(s, 0.0f);
    }
#pragma unroll
    for (int h = 0; h < 2; h++) {
        int j0 = h * 32;
        float4 acc[8];
#pragma unroll
        for (int jj = 0; jj < 8; jj++)
            acc[jj] = *(const float4*)&sb2[j0 + jj * 4];
#pragma unroll
        for (int c = 0; c < KW; c++) {
            float tc = t[c];
#pragma unroll
            for (int jj = 0; jj < 8; jj++) {
                float4 w = *(const float4*)&sw2[c * KW + j0 + jj * 4];
                acc[jj].x += tc * w.x; acc[jj].y += tc * w.y;
                acc[jj].z += tc * w.z; acc[jj].w += tc * w.w;
            }
        }
#pragma unroll
        for (int jj = 0; jj < 8; jj++) {
            float4 r = acc[jj];
            r.x = fmaxf(r.x, 0.f); r.y = fmaxf(r.y, 0.f);
            r.z = fmaxf(r.z, 0.f); r.w = fmaxf(r.w, 0.f);
            *(float4*)&K[(size_t)e * KW + j0 + jj * 4] = r;
        }
    }
}

// ---------------- initial h gather into per-block transposed layout ----------------
// hgt[block][k][r] = h[anodes[block*8+r]][k]

__global__ void k_gath(const float* __restrict__ h,
        const int* __restrict__ anodes1, const int* __restrict__ dna1,
        float* __restrict__ hg1,
        const int* __restrict__ anodesb, const int* __restrict__ dnab,
        float* __restrict__ hgb) {
    int t = blockIdx.x * blockDim.x + threadIdx.x;
    if (t < NN * WID) {
        int r = t >> 5, k = t & 31;
        if (r < dna1[0])
            hg1[(r >> 3) * 256 + k * 8 + (r & 7)] = h[(size_t)anodes1[r] * WID + k];
    } else if (t < 2 * NN * WID) {
        int u = t - NN * WID;
        int r = u >> 5, k = u & 31;
        if (r < dnab[0])
            hgb[(r >> 3) * 256 + k * 8 + (r & 7)] = h[(size_t)anodesb[r] * WID + k];
    }
}

// ---------------- fused per-depth sweep, dual-graph, NBL=8, 576 threads ----------------
// Phase A: G rows (8 x 2080) in LDS. Thread owns one col-quad x all 8 rows
// (32 acc VGPRs); h read as wave-uniform float4 pairs from hgt (L1-resident,
// no LDS); M float4 read once per block (dup=1).
// Phase B: contiguous src-sorted edge range, 72 groups of 8 lanes, rk_s holds ranks.

__global__ __launch_bounds__(TPB_F, 2) void k_fuse3(
        const int* __restrict__ rkA, const int* __restrict__ dstA,
        const int* __restrict__ aoffA, const int* __restrict__ dnaA,
        const float* __restrict__ KA, const float* __restrict__ MA,
        const float* __restrict__ hgA, float* __restrict__ aggA,
        const int* __restrict__ rkB, const int* __restrict__ dstB,
        const int* __restrict__ aoffB, const int* __restrict__ dnaB,
        const float* __restrict__ KB, const float* __restrict__ MB,
        const float* __restrict__ hgB, float* __restrict__ aggB,
        int nblkA) {
    __shared__ float sG[NBL * GR];   // 66.7 KB
    const int *rk_s, *dst_s, *aoff;
    const float *Ks, *M, *hg;
    float* agg;
    int bid, na;
    if ((int)blockIdx.x < nblkA) {
        bid = blockIdx.x; na = dnaA[0];
        rk_s = rkA; dst_s = dstA; aoff = aoffA; Ks = KA; M = MA; hg = hgA; agg = aggA;
    } else {
        bid = blockIdx.x - nblkA; na = dnaB[0];
        rk_s = rkB; dst_s = dstB; aoff = aoffB; Ks = KB; M = MB; hg = hgB; agg = aggB;
    }
    int a0 = bid * NBL;
    if (a0 >= na) return;
    int t = threadIdx.x;
    // phase A
    if (t < NQ) {
        int col = t * 4;
        const float* hb = hg + bid * 256;   // [32][8], 1 KB, L1-resident
        float4 acc[NBL];
#pragma unroll
        for (int r = 0; r < NBL; r++) acc[r] = make_float4(0.f, 0.f, 0.f, 0.f);
#pragma unroll 8
        for (int k = 0; k < 32; k++) {
            float4 mv = *(const float4*)&M[(size_t)k * GC + col];
            float4 ha = *(const float4*)&hb[k * 8];
            float4 hc = *(const float4*)&hb[k * 8 + 4];
            float hv[NBL] = {ha.x, ha.y, ha.z, ha.w, hc.x, hc.y, hc.z, hc.w};
#pragma unroll
            for (int r = 0; r < NBL; r++) {
                acc[r].x += hv[r] * mv.x; acc[r].y += hv[r] * mv.y;
                acc[r].z += hv[r] * mv.z; acc[r].w += hv[r] * mv.w;
            }
        }
#pragma unroll
        for (int r = 0; r < NBL; r++)
            *(float4*)&sG[r * GR + col] = acc[r];
    }
    __syncthreads();
    // phase B: 72 groups of 8 lanes
    int a1 = a0 + NBL; if (a1 > na) a1 = na;
    int e_lo = aoff[a0];
    int e_hi = aoff[a1];
    int g = t >> 3;
    int q4 = (t & 7) * 4;
    for (int e = e_lo + g; e < e_hi; e += TPB_F / 8) {
        int row = rk_s[e] - a0;
        int dst = dst_s[e];
        const float* Kr = Ks + (size_t)e * KW;
        int gb = row * GR;
        float4 v0 = *(const float4*)&sG[gb + 2048 + q4];   // bias-fold column
        float4 v1 = make_float4(0.f, 0.f, 0.f, 0.f);
        float4 v2 = v1, v3 = v1;
#pragma unroll
        for (int c4 = 0; c4 < 16; c4++) {
            float4 kv = *(const float4*)&Kr[c4 * 4];
            float4 g0 = *(const float4*)&sG[gb + (c4 * 4 + 0) * 32 + q4];
            float4 g1 = *(const float4*)&sG[gb + (c4 * 4 + 1) * 32 + q4];
            float4 g2 = *(const float4*)&sG[gb + (c4 * 4 + 2) * 32 + q4];
            float4 g3 = *(const float4*)&sG[gb + (c4 * 4 + 3) * 32 + q4];
            v0.x += kv.x * g0.x; v0.y += kv.x * g0.y; v0.z += kv.x * g0.z; v0.w += kv.x * g0.w;
            v1.x += kv.y * g1.x; v1.y += kv.y * g1.y; v1.z += kv.y * g1.z; v1.w += kv.y * g1.w;
            v2.x += kv.z * g2.x; v2.y += kv.z * g2.y; v2.z += kv.z * g2.z; v2.w += kv.z * g2.w;
            v3.x += kv.w * g3.x; v3.y += kv.w * g3.y; v3.z += kv.w * g3.z; v3.w += kv.w * g3.w;
        }
        float4 m;
        m.x = v0.x + v1.x + v2.x + v3.x;
        m.y = v0.y + v1.y + v2.y + v3.y;
        m.z = v0.z + v1.z + v2.z + v3.z;
        m.w = v0.w + v1.w + v2.w + v3.w;
        float* ap = agg + (size_t)dst * WID + q4;
        unsafeAtomicAdd(ap + 0, m.x);
        unsafeAtomicAdd(ap + 1, m.y);
        unsafeAtomicAdd(ap + 2, m.z);
        unsafeAtomicAdd(ap + 3, m.w);
    }
}

// ---------------- node update (in place) + hgt regather for next depth ----------------

__global__ __launch_bounds__(256) void k_node2(float* __restrict__ h,
        const float* __restrict__ agg1, const float* __restrict__ aggb,
        const float* __restrict__ inv1, const float* __restrict__ invb,
        const float* __restrict__ x, const float* __restrict__ fc1w,
        const float* __restrict__ fc1b,
        const float* __restrict__ rs, const float* __restrict__ bs,
        const int* __restrict__ arank1, const int* __restrict__ anodes1,
        const int* __restrict__ dna1, float* __restrict__ hg1,
        const int* __restrict__ arankb, const int* __restrict__ anodesb,
        const int* __restrict__ dnab, float* __restrict__ hgb) {
    __shared__ float sR[1024];
    __shared__ float sB[32];
    for (int i = threadIdx.x; i < 1024; i += 256) sR[i] = rs[i];
    if (threadIdx.x < 32) sB[threadIdx.x] = bs[threadIdx.x];
    __syncthreads();
    int t = blockIdx.x * 256 + threadIdx.x;
    if (t >= NN * WID) return;
    int n = t >> 5, j = t & 31;
    float s = agg1[t] * inv1[n] + aggb[t] * invb[n] + sB[j];
    const float* hr = h + (size_t)n * WID;
#pragma unroll
    for (int i = 0; i < 32; i++) s += hr[i] * sR[i * 32 + j];
    float h0v = x[n] * fc1w[j] + fc1b[j];
    float val = fmaxf(s, 0.0f) + h0v;
    h[t] = val;   // safe: row n is read/written only by its own (wave-local) threads
    int r1 = arank1[n];
    if (r1 < dna1[0] && anodes1[r1] == n)
        hg1[(r1 >> 3) * 256 + j * 8 + (r1 & 7)] = val;
    int rb = arankb[n];
    if (rb < dnab[0] && anodesb[rb] == n)
        hgb[(rb >> 3) * 256 + j * 8 + (rb & 7)] = val;
}

__global__ void k_fc2(const float* __restrict__ h, const float* __restrict__ w,
                      const float* __restrict__ b, float* __restrict__ out) {
    int n = blockIdx.x * blockDim.x + threadIdx.x;
    if (n >= NN) return;
    const float4* hv = (const float4*)(h + (size_t)n * WID);
    const float4* wv = (const float4*)w;
    float s = b[0];
#pragma unroll
    for (int q = 0; q < 8; q++) {
        float4 a = hv[q], c = wv[q];
        s += a.x * c.x + a.y * c.y + a.z * c.z + a.w * c.w;
    }
    out[n] = s;
}

// ---------------- launch ----------------

extern "C" void kernel_launch(void* const* d_in, const int* in_sizes, int n_in,
                              void* d_out, int out_size, void* d_ws, size_t ws_size,
                              hipStream_t stream) {
    const float* x    = (const float*)d_in[0];
    const int*   ei   = (const int*)d_in[1];
    const float* ea   = (const float*)d_in[2];
    const int*   eib  = (const int*)d_in[3];
    const float* eab  = (const float*)d_in[4];
    const float* fc1w = (const float*)d_in[5];
    const float* fc1b = (const float*)d_in[6];
    const float* fc2w = (const float*)d_in[7];
    const float* fc2b = (const float*)d_in[8];
    const float* k1w1 = (const float*)d_in[9];
    const float* k1b1 = (const float*)d_in[10];
    const float* k1w2 = (const float*)d_in[11];
    const float* k1b2 = (const float*)d_in[12];
    const float* k1w3 = (const float*)d_in[13];
    const float* k1b3 = (const float*)d_in[14];
    const float* root1= (const float*)d_in[15];
    const float* bias1= (const float*)d_in[16];
    const float* k2w1 = (const float*)d_in[17];
    const float* k2b1 = (const float*)d_in[18];
    const float* k2w2 = (const float*)d_in[19];
    const float* k2b2 = (const float*)d_in[20];
    const float* k2w3 = (const float*)d_in[21];
    const float* k2b3 = (const float*)d_in[22];
    const float* root2= (const float*)d_in[23];
    const float* bias2= (const float*)d_in[24];

    float* p = (float*)d_ws;
    auto alloc = [&](size_t nflt) { float* r = p; p += nflt; return r; };
    float* K1   = alloc((size_t)EM * KW);     // sorted (by src) order
    float* Kb   = alloc((size_t)EBN * KW);
    float* hA   = alloc((size_t)NN * WID);
    float* agg1 = alloc((size_t)NN * WID);    // agg1+aggb contiguous: single memset
    float* aggb = alloc((size_t)NN * WID);
    float* hg1  = alloc((size_t)2500 * 256);  // [block][32][8]
    float* hgb  = alloc((size_t)2500 * 256);
    float* inv1 = alloc(NN);
    float* invb = alloc(NN);
    float* rs   = alloc(1024);
    float* bs   = alloc(32);
    int*   cnt1 = (int*)alloc(NN);   // cnt1,cntb,cs1,csb contiguous: single memset
    int*   cntb = (int*)alloc(NN);
    int*   cs1  = (int*)alloc(NN);
    int*   csb  = (int*)alloc(NN);
    int*   cur1 = (int*)alloc(NN);
    int*   curb = (int*)alloc(NN);
    int*   arank1 = (int*)alloc(NN);
    int*   arankb = (int*)alloc(NN);
    int*   anodes1= (int*)alloc(NN);
    int*   anodesb= (int*)alloc(NN);
    int*   aoff1  = (int*)alloc(NN + 1);
    int*   aoffb  = (int*)alloc(NN + 1);
    int*   dna1   = (int*)alloc(1);
    int*   dnab   = (int*)alloc(1);
    int*   perm1= (int*)alloc(EM);
    int*   permb= (int*)alloc(EBN);
    int*   rk1  = (int*)alloc(EM);
    int*   dst1 = (int*)alloc(EM);
    int*   rkb  = (int*)alloc(EBN);
    int*   dstb = (int*)alloc(EBN);
    float* M1   = alloc(32 * GC);
    float* M2   = alloc(32 * GC);

    hipMemsetAsync(cnt1, 0, 4 * NN * sizeof(int), stream);
    k_h0<<<(NN * WID + 255) / 256, 256, 0, stream>>>(x, fc1w, fc1b, hA);
    k_count4<<<(2 * EM + 2 * EBN + 255) / 256, 256, 0, stream>>>(ei, eib, cs1, cnt1, csb, cntb);
    k_scan3<<<2, 1024, 0, stream>>>(cs1, cur1, arank1, anodes1, aoff1, dna1, EM,
                                    csb, curb, arankb, anodesb, aoffb, dnab, EBN);
    k_inv2<<<(2 * NN + 255) / 256, 256, 0, stream>>>(cnt1, inv1, cntb, invb);
    k_scatter3<<<(EM + EBN + 255) / 256, 256, 0, stream>>>(ei, cur1, perm1, eib, curb, permb);
    k_permidx3<<<(EM + EBN + 255) / 256, 256, 0, stream>>>(ei, perm1, arank1, rk1, dst1,
                                                           eib, permb, arankb, rkb, dstb);
    int nmb = (EM + 255) / 256;
    k_mlp3<<<nmb + (EBN + 255) / 256, 256, 0, stream>>>(
        ea, perm1, k1w1, k1b1, k1w2, k1b2, K1,
        eab, permb, k2w1, k2b1, k2w2, k2b2, Kb, nmb);
    k_permM3<<<(64 * GC + 1056 + 255) / 256, 256, 0, stream>>>(
        k1w3, k1b3, M1, k2w3, k2b3, M2, root1, bias1, root2, bias2, rs, bs);
    k_gath<<<(2 * NN * WID + 255) / 256, 256, 0, stream>>>(hA, anodes1, dna1, hg1,
                                                           anodesb, dnab, hgb);

    int nblkA = (NN + NBL - 1) / NBL;           // 2500
    int fgrid = nblkA * 2;                      // main + boundary halves
    for (int d = 0; d < NDEPTH; d++) {
        hipMemsetAsync(agg1, 0, (size_t)2 * NN * WID * sizeof(float), stream);
        k_fuse3<<<fgrid, TPB_F, 0, stream>>>(rk1, dst1, aoff1, dna1, K1, M1, hg1, agg1,
                                             rkb, dstb, aoffb, dnab, Kb, M2, hgb, aggb,
                                             nblkA);
        k_node2<<<(NN * WID + 255) / 256, 256, 0, stream>>>(hA, agg1, aggb, inv1, invb,
                                                            x, fc1w, fc1b, rs, bs,
                                                            arank1, anodes1, dna1, hg1,
                                                            arankb, anodesb, dnab, hgb);
    }
    k_fc2<<<(NN + 255) / 256, 256, 0, stream>>>(hA, fc2w, fc2b, (float*)d_out);
}